// Round 2
// baseline (3282.717 us; speedup 1.0000x reference)
//
#include <hip/hip_runtime.h>
#include <hip/hip_bf16.h>
#include <cstdint>
#include <cstddef>

#define NN 20000
#define NE 200000
#define NG 128
#define HID 256
#define NREP 8   // contention-splitting replicas for graph-level scatter sums

typedef __bf16 bfrag8 __attribute__((ext_vector_type(8)));  // 8 bf16 (4 VGPRs)
typedef float  accf4  __attribute__((ext_vector_type(4)));  // 4 fp32 acc

__device__ __forceinline__ unsigned short f2bf(float f) {
    union { float f; unsigned int i; } x; x.f = f;
    unsigned int r = x.i + 0x7fffu + ((x.i >> 16) & 1u);  // RNE
    return (unsigned short)(r >> 16);
}
__device__ __forceinline__ __bf16 f2bf16t(float f) {
    union { unsigned short u; __bf16 b; } x; x.u = f2bf(f); return x.b;
}
__device__ __forceinline__ float sspf(float x) {
    // softplus(x) - log(2), numerically stable
    return fmaxf(x, 0.f) + log1pf(expf(-fabsf(x))) - 0.69314718055994530942f;
}

// async 16B global -> LDS (per-lane global addr, lane-linear LDS dest: base + lane*16)
__device__ __forceinline__ void gload_lds16(const void* g, void* l) {
    __builtin_amdgcn_global_load_lds(
        (const __attribute__((address_space(1))) unsigned int*)g,
        (__attribute__((address_space(3))) unsigned int*)l,
        16, 0, 0);
}

// A-operand spec: virtual A[M, nblocks*256] = concat of up to 4 [.,256] sources,
// each with optional row-index indirection (nullptr => identity), optional per-row
// count (value scaled by 1/max(cnt,1) -- f32 blocks only; fuses scatter-mean), and
// per-block dtype flag (f32mask bit b set => base[b] is const float*, else bf16).
struct ASpec {
    const void* base[4];
    const int* idx[4];
    const float* rowcnt[4];
    int f32mask;
    int nblocks;
};

// Epilogue scatter spec: fused scatter-add of the post-ssp value v (pre-residual).
//   sc1: plain atomicAdd to sc1_out[sc1_idx[r]*HID + c]           (e2n_sum, NN rows)
//   sc2: replicated (x NREP by blockIdx) atomicAdd, NG-row target (e2g_sum / n2g_sum)
struct EpiSpec {
    float* sc1_out; const int* sc1_idx;
    float* sc2_out; const int* sc2_idx;
};

// out[M,256] = ssp( A_virtual[M,K] @ Wbf16[256,K]^T ) (+ resid_f32), out f32 or bf16.
//
// LDS-staged MFMA GEMM, tile = 128 rows x 256 cols, 8 waves (2 row-groups x 4
// col-groups), K-step 32. LDS/buf: A 128x32 (8 x 1KB subtiles) + W 256x32 (16
// subtiles) = 24KB, double-buffered = 48KB -> 3 blocks/CU (24 waves) for latency
// hiding. Fragment-ordered layout (subtile base + lane*16): linear, conflict-free
// ds_read_b128, matches global_load_lds' lane-linear destination.
// Wave w stages A-subtile w (rows w*16..w*16+15, per-lane gather addresses ok) and
// W-subtiles 2w, 2w+1. f32 A-sources go through VGPR convert (+rowscale) + ds_write.
//
// In-place safe when out aliases an identity-indexed A block: each block reads only
// its own 128 rows; all global A reads are drained by the barrier after their STAGE;
// clamped tail rows never store/scatter (r < M guard).
__global__ __launch_bounds__(512, 6) void gemm_ssp_kernel(
    ASpec A, EpiSpec E, const unsigned short* __restrict__ W,
    void* __restrict__ out, int out_f32,
    const float* __restrict__ resid, int M)
{
    __shared__ unsigned short lds[2][12288];   // 2 x 24KB: [A: 8*512 | W: 16*512] shorts

    const int K    = A.nblocks * HID;
    const int lane = threadIdx.x & 63;
    const int wave = threadIdx.x >> 6;
    const int l15  = lane & 15;
    const int kg   = lane >> 4;
    const int wr   = wave >> 2;      // row-group 0..1
    const int wc   = wave & 3;       // col-group 0..3
    const int rowbase = blockIdx.x * 128;

    // ---- staging setup: per-thread fixed source pointers ----
    const int arow = rowbase + wave * 16 + l15;
    const int arc  = arow < M ? arow : (M - 1);
    float rs0 = 1.f, rs1 = 1.f, rs2 = 1.f, rs3 = 1.f;
    auto mkap = [&](int b, float& rs) -> const char* {
        if (b >= A.nblocks) return (const char*)A.base[0];
        const int rid = A.idx[b] ? A.idx[b][arc] : arc;
        if (A.rowcnt[b]) rs = 1.f / fmaxf(A.rowcnt[b][rid], 1.f);
        const int e4 = (A.f32mask >> b) & 1;
        return (const char*)A.base[b] + (size_t)rid * (size_t)(HID * (e4 ? 4 : 2));
    };
    const char* ap0 = mkap(0, rs0);
    const char* ap1 = mkap(1, rs1);
    const char* ap2 = mkap(2, rs2);
    const char* ap3 = mkap(3, rs3);

    // W: this thread stages rows (wave*2+j)*16 + l15, k-chunk kg, j=0..1.
    const unsigned short* wq0 = W + (size_t)((wave * 2 + 0) * 16 + l15) * K + kg * 8;
    const unsigned short* wq1 = W + (size_t)((wave * 2 + 1) * 16 + l15) * K + kg * 8;

    auto STAGE = [&](int buf, int kt) {
        unsigned short* ldsb = &lds[buf][0];
        const int b   = kt >> 3;                    // which 256-col source block
        const int kin = (kt & 7) * 32 + kg * 8;     // element offset within source row
        const char* ap = (b == 0) ? ap0 : (b == 1) ? ap1 : (b == 2) ? ap2 : ap3;
        if ((A.f32mask >> b) & 1) {
            const float rs = (b == 0) ? rs0 : (b == 1) ? rs1 : (b == 2) ? rs2 : rs3;
            const float* p = (const float*)ap + kin;
            const float4 x = ((const float4*)p)[0];
            const float4 y = ((const float4*)p)[1];
            bfrag8 f;
            f[0] = f2bf16t(x.x * rs); f[1] = f2bf16t(x.y * rs);
            f[2] = f2bf16t(x.z * rs); f[3] = f2bf16t(x.w * rs);
            f[4] = f2bf16t(y.x * rs); f[5] = f2bf16t(y.y * rs);
            f[6] = f2bf16t(y.z * rs); f[7] = f2bf16t(y.w * rs);
            *(bfrag8*)((char*)ldsb + wave * 1024 + lane * 16) = f;
        } else {
            gload_lds16((const unsigned short*)ap + kin, (char*)ldsb + wave * 1024);
        }
        const int koff = kt * 32;
        gload_lds16(wq0 + koff, (char*)ldsb + 8192 + (wave * 2 + 0) * 1024);
        gload_lds16(wq1 + koff, (char*)ldsb + 8192 + (wave * 2 + 1) * 1024);
    };

    accf4 acc[4][4];
    #pragma unroll
    for (int m = 0; m < 4; m++)
        #pragma unroll
        for (int n = 0; n < 4; n++)
            acc[m][n] = (accf4){0.f, 0.f, 0.f, 0.f};

    const int ksteps = A.nblocks * 8;

    STAGE(0, 0);
    __syncthreads();                                // buf0 ready (vmcnt+lgkm drained)

    for (int kt = 0; kt < ksteps; ++kt) {
        const int cur = kt & 1;
        if (kt + 1 < ksteps) STAGE(cur ^ 1, kt + 1);

        const char* ldsb = (const char*)&lds[cur][0];
        bfrag8 af[4], bf[4];
        #pragma unroll
        for (int m = 0; m < 4; m++)
            af[m] = *(const bfrag8*)(ldsb + (wr * 4 + m) * 1024 + lane * 16);
        #pragma unroll
        for (int n = 0; n < 4; n++)
            bf[n] = *(const bfrag8*)(ldsb + 8192 + (wc * 4 + n) * 1024 + lane * 16);
        #pragma unroll
        for (int m = 0; m < 4; m++)
            #pragma unroll
            for (int n = 0; n < 4; n++)
                acc[m][n] = __builtin_amdgcn_mfma_f32_16x16x32_bf16(af[m], bf[n], acc[m][n], 0, 0, 0);

        __syncthreads();   // readers done with buf[cur] + next buf's loads drained
    }

    // epilogue: D fragment (col = l15, row = kg*4 + rg)
    float* sc2base = E.sc2_out ? E.sc2_out + (size_t)(blockIdx.x & (NREP - 1)) * NG * HID
                               : nullptr;
    #pragma unroll
    for (int m = 0; m < 4; m++) {
        #pragma unroll
        for (int rg = 0; rg < 4; rg++) {
            const int r = rowbase + wr * 64 + m * 16 + kg * 4 + rg;
            if (r < M) {
                const int i1 = E.sc1_out ? E.sc1_idx[r] : 0;
                const int i2 = sc2base   ? E.sc2_idx[r] : 0;
                #pragma unroll
                for (int n = 0; n < 4; n++) {
                    const int c = wc * 64 + n * 16 + l15;
                    const size_t off = (size_t)r * HID + c;
                    float v = sspf(acc[m][n][rg]);
                    if (E.sc1_out) atomicAdd(&E.sc1_out[(size_t)i1 * HID + c], v);
                    if (sc2base)   atomicAdd(&sc2base[(size_t)i2 * HID + c], v);
                    if (resid) v += resid[off];
                    if (out_f32) ((float*)out)[off] = v;
                    else ((unsigned short*)out)[off] = f2bf(v);
                }
            }
        }
    }
}

__global__ void cvt_w_kernel(const float* __restrict__ src, unsigned short* __restrict__ dst, int n) {
    int i = blockIdx.x * 256 + threadIdx.x;
    if (i < n) dst[i] = f2bf(src[i]);
}

__global__ void be_counts_kernel(const int* __restrict__ src, const int* __restrict__ dst,
                                 const int* __restrict__ batch, int* __restrict__ be,
                                 float* __restrict__ cnt_n, float* __restrict__ cnt_eg) {
    int e = blockIdx.x * 256 + threadIdx.x;
    if (e < NE) {
        int b = batch[src[e]];
        be[e] = b;
        atomicAdd(&cnt_n[dst[e]], 1.f);
        atomicAdd(&cnt_eg[b], 1.f);
    }
}

__global__ void node_counts_kernel(const int* __restrict__ batch, float* __restrict__ cnt_ng) {
    int i = blockIdx.x * 256 + threadIdx.x;
    if (i < NN) atomicAdd(&cnt_ng[batch[i]], 1.f);
}

// sum NREP replicas, divide by per-row count, emit bf16. M = NG.
__global__ void mean_rep_kernel(const float* __restrict__ sums, const float* __restrict__ cnt,
                                unsigned short* __restrict__ out) {
    int gid = blockIdx.x * 256 + threadIdx.x;
    if (gid < NG * HID) {
        float s = 0.f;
        #pragma unroll
        for (int rp = 0; rp < NREP; rp++) s += sums[(size_t)rp * NG * HID + gid];
        out[gid] = f2bf(s / fmaxf(cnt[gid >> 8], 1.f));
    }
}

extern "C" void kernel_launch(void* const* d_in, const int* in_sizes, int n_in,
                              void* d_out, int out_size, void* d_ws, size_t ws_size,
                              hipStream_t stream)
{
    (void)in_sizes; (void)n_in; (void)out_size; (void)ws_size;
    const float* node_feats = (const float*)d_in[0];
    const float* edge_feats = (const float*)d_in[1];
    const float* glob_feats = (const float*)d_in[2];
    const int* edge_index   = (const int*)d_in[3];
    const int* batch        = (const int*)d_in[4];
    const float* Wf[9] = {
        (const float*)d_in[5],  (const float*)d_in[6],  (const float*)d_in[7],
        (const float*)d_in[8],  (const float*)d_in[9],  (const float*)d_in[10],
        (const float*)d_in[11], (const float*)d_in[12], (const float*)d_in[13],
    };
    const int Wn[9] = { HID*HID, HID*HID, HID*HID,
                        HID*4*HID, HID*3*HID, HID*3*HID,
                        HID*HID, HID*HID, HID*HID };

    const int* src = edge_index;        // edge_index[0]
    const int* dst = edge_index + NE;   // edge_index[1]

    float* out_n = (float*)d_out;                       // [NN,256] f32
    float* out_e = out_n + (size_t)NN * HID;            // [NE,256] f32
    float* out_g = out_e + (size_t)NE * HID;            // [NG,256] f32

    // ws layout (~38 MB). Zero-init region first -> single memsetAsync.
    char* ws = (char*)d_ws;
    size_t off = 0;
    auto alloc = [&](size_t bytes) -> char* {
        char* p = ws + off; off += (bytes + 255) & ~(size_t)255; return p;
    };
    float* e2g_sum = (float*)alloc((size_t)NREP * NG * HID * 4);   // 1 MB, replicated
    float* n2g_sum = (float*)alloc((size_t)NREP * NG * HID * 4);   // 1 MB, replicated
    float* cnt_n   = (float*)alloc((size_t)NN * 4);
    float* cnt_eg  = (float*)alloc((size_t)NG * 4);
    float* cnt_ng  = (float*)alloc((size_t)NG * 4);
    size_t zero_bytes = off;
    hipMemsetAsync(d_ws, 0, zero_bytes, stream);

    int* be                  = (int*)alloc((size_t)NE * 4);
    unsigned short* n1       = (unsigned short*)alloc((size_t)NN * HID * 2);
    unsigned short* g1       = (unsigned short*)alloc((size_t)NG * HID * 2);
    unsigned short* n_mid    = (unsigned short*)alloc((size_t)NN * HID * 2);
    unsigned short* n2g_mean = (unsigned short*)alloc((size_t)NG * HID * 2);
    unsigned short* e2g_mean = (unsigned short*)alloc((size_t)NG * HID * 2);
    unsigned short* g_mid    = (unsigned short*)alloc((size_t)NG * HID * 2);
    unsigned short* Wb[9];
    for (int i = 0; i < 9; i++) Wb[i] = (unsigned short*)alloc((size_t)Wn[i] * 2);

    // Aliases into d_out:
    float* e1      = out_e;   // stage-1 edge activations, f32, in place
    float* e_mid   = out_e;   // edge-MLP output, f32, in place (identity rows)
    float* e2n_sum = out_n;   // f32 atomic target; dead before final node GEMM writes out_n
    hipMemsetAsync(e2n_sum, 0, (size_t)NN * HID * 4, stream);

    // weights -> bf16 (9 tiny launches, 1M elements total)
    for (int i = 0; i < 9; i++)
        cvt_w_kernel<<<(Wn[i] + 255) / 256, 256, 0, stream>>>(Wf[i], Wb[i], Wn[i]);

    be_counts_kernel<<<(NE + 255) / 256, 256, 0, stream>>>(src, dst, batch, be, cnt_n, cnt_eg);
    node_counts_kernel<<<(NN + 255) / 256, 256, 0, stream>>>(batch, cnt_ng);

    auto launch_gemm = [&](const ASpec& A, const EpiSpec& E, const unsigned short* W,
                           void* o, int of32, const float* resid, int M) {
        gemm_ssp_kernel<<<(M + 127) / 128, 512, 0, stream>>>(A, E, W, o, of32, resid, M);
    };
    const EpiSpec enone{};

    // stage 1: lin_*_1 + ssp
    { ASpec a{}; a.base[0] = node_feats; a.f32mask = 1; a.nblocks = 1;
      launch_gemm(a, enone, Wb[0], n1, 0, nullptr, NN); }
    { ASpec a{}; a.base[0] = edge_feats; a.f32mask = 1; a.nblocks = 1;
      launch_gemm(a, enone, Wb[1], e1, 1, nullptr, NE); }
    { ASpec a{}; a.base[0] = glob_feats; a.f32mask = 1; a.nblocks = 1;
      launch_gemm(a, enone, Wb[2], g1, 0, nullptr, NG); }

    // EdgeModel: gather-concat fused into A-load, K=1024 (in place on out_e);
    // fused scatter-add of e into e2n_sum (by dst) and e2g_sum replicas (by be).
    { ASpec a{};
      a.base[0] = n1; a.idx[0] = src;
      a.base[1] = n1; a.idx[1] = dst;
      a.base[2] = e1; a.idx[2] = nullptr;
      a.base[3] = g1; a.idx[3] = be;
      a.f32mask = 0b0100;   // block 2 (e1) is f32
      a.nblocks = 4;
      EpiSpec e{}; e.sc1_out = e2n_sum; e.sc1_idx = dst;
      e.sc2_out = e2g_sum; e.sc2_idx = be;
      launch_gemm(a, e, Wb[3], e_mid, 1, nullptr, NE); }

    // NodeModel: K=768 -> n_mid bf16; e2n mean fused via rowcnt; fused n->graph scatter.
    { ASpec a{};
      a.base[0] = n1;
      a.base[1] = e2n_sum; a.rowcnt[1] = cnt_n;
      a.base[2] = g1; a.idx[2] = batch;
      a.f32mask = 0b010;    // block 1 (e2n_sum) is f32
      a.nblocks = 3;
      EpiSpec e{}; e.sc2_out = n2g_sum; e.sc2_idx = batch;
      launch_gemm(a, e, Wb[4], n_mid, 0, nullptr, NN); }

    // graph-level means (replica-reduce, tiny)
    mean_rep_kernel<<<(NG * HID + 255) / 256, 256, 0, stream>>>(n2g_sum, cnt_ng, n2g_mean);
    mean_rep_kernel<<<(NG * HID + 255) / 256, 256, 0, stream>>>(e2g_sum, cnt_eg, e2g_mean);

    // GlobalModel: K=768 -> g_mid bf16
    { ASpec a{};
      a.base[0] = n2g_mean; a.base[1] = e2g_mean; a.base[2] = g1;
      a.f32mask = 0; a.nblocks = 3;
      launch_gemm(a, enone, Wb[5], g_mid, 0, nullptr, NG); }

    // final lin_*_2 + ssp + residual -> f32 d_out (edge runs in place on out_e)
    { ASpec a{}; a.base[0] = n_mid; a.f32mask = 0; a.nblocks = 1;
      launch_gemm(a, enone, Wb[6], out_n, 1, node_feats, NN); }
    { ASpec a{}; a.base[0] = e_mid; a.f32mask = 1; a.nblocks = 1;
      launch_gemm(a, enone, Wb[7], out_e, 1, edge_feats, NE); }
    { ASpec a{}; a.base[0] = g_mid; a.f32mask = 0; a.nblocks = 1;
      launch_gemm(a, enone, Wb[8], out_g, 1, glob_feats, NG); }
}

// Round 4
// 3109.512 us; speedup vs baseline: 1.0557x; 1.0557x over previous
//
#include <hip/hip_runtime.h>
#include <hip/hip_bf16.h>
#include <cstdint>
#include <cstddef>

#define NN 20000
#define NE 200000
#define NG 128
#define HID 256
#define E2G_CHUNKS 64   // edge chunks for the LDS-binned e2g reduction

typedef __bf16 bfrag8 __attribute__((ext_vector_type(8)));  // 8 bf16 (4 VGPRs)
typedef float  accf4  __attribute__((ext_vector_type(4)));  // 4 fp32 acc

__device__ __forceinline__ unsigned short f2bf(float f) {
    union { float f; unsigned int i; } x; x.f = f;
    unsigned int r = x.i + 0x7fffu + ((x.i >> 16) & 1u);  // RNE
    return (unsigned short)(r >> 16);
}
__device__ __forceinline__ __bf16 f2bf16t(float f) {
    union { unsigned short u; __bf16 b; } x; x.u = f2bf(f); return x.b;
}
__device__ __forceinline__ float bf2f(unsigned short u) {
    union { unsigned int i; float f; } x; x.i = ((unsigned int)u) << 16; return x.f;
}
__device__ __forceinline__ float sspf(float x) {
    // softplus(x) - log(2), numerically stable
    return fmaxf(x, 0.f) + log1pf(expf(-fabsf(x))) - 0.69314718055994530942f;
}

// async 16B global -> LDS (per-lane global addr, lane-linear LDS dest: base + lane*16)
__device__ __forceinline__ void gload_lds16(const void* g, void* l) {
    __builtin_amdgcn_global_load_lds(
        (const __attribute__((address_space(1))) unsigned int*)g,
        (__attribute__((address_space(3))) unsigned int*)l,
        16, 0, 0);
}

// A-operand spec: virtual A[M, nblocks*256] = concat of up to 4 [.,256] sources,
// each with optional row-index indirection (nullptr => identity) and a per-block
// dtype flag (f32mask bit b set => base[b] is const float*, else bf16).
struct ASpec {
    const void* base[4];
    const int* idx[4];
    int f32mask;
    int nblocks;
};

// out[M,256] = ssp( A_virtual[M,K] @ Wbf16[256,K]^T ) (+ resid_f32), out f32 or bf16.
//
// LDS-staged MFMA GEMM, tile = 128 rows x 256 cols, 8 waves (2 row-groups x 4
// col-groups), K-step 32. LDS/buf: A 128x32 (8 x 1KB subtiles) + W 256x32 (16
// subtiles) = 24KB, double-buffered = 48KB -> 3 blocks/CU (24 waves, 61% occupancy
// measured) for latency hiding. Fragment-ordered layout (subtile base + lane*16):
// linear, conflict-free ds_read_b128, matches global_load_lds' lane-linear dest.
// Wave w stages A-subtile w (rows w*16..w*16+15, per-lane gather addresses ok) and
// W-subtiles 2w, 2w+1. f32 A-sources go through VGPR convert + ds_write.
//
// NOTE (r2 lesson): no global atomics in the epilogue — device-scope f32 atomics
// execute memory-side (past per-XCD L2) and ballooned HBM traffic 0.76 -> 3.7 GB.
//
// In-place safe when out aliases an identity-indexed A block: each block reads only
// its own 128 rows; all global A reads are drained by the barrier after their STAGE;
// clamped tail rows never store (r < M guard).
__global__ __launch_bounds__(512, 6) void gemm_ssp_kernel(
    ASpec A, const unsigned short* __restrict__ W,
    void* __restrict__ out, int out_f32,
    const float* __restrict__ resid, int M)
{
    __shared__ unsigned short lds[2][12288];   // 2 x 24KB: [A: 8*512 | W: 16*512] shorts

    const int K    = A.nblocks * HID;
    const int lane = threadIdx.x & 63;
    const int wave = threadIdx.x >> 6;
    const int l15  = lane & 15;
    const int kg   = lane >> 4;
    const int wr   = wave >> 2;      // row-group 0..1
    const int wc   = wave & 3;       // col-group 0..3
    const int rowbase = blockIdx.x * 128;

    // ---- staging setup: per-thread fixed source pointers ----
    const int arow = rowbase + wave * 16 + l15;
    const int arc  = arow < M ? arow : (M - 1);
    auto mkap = [&](int b) -> const char* {
        if (b >= A.nblocks) return (const char*)A.base[0];
        const int rid = A.idx[b] ? A.idx[b][arc] : arc;
        const int e4 = (A.f32mask >> b) & 1;
        return (const char*)A.base[b] + (size_t)rid * (size_t)(HID * (e4 ? 4 : 2));
    };
    const char* ap0 = mkap(0);
    const char* ap1 = mkap(1);
    const char* ap2 = mkap(2);
    const char* ap3 = mkap(3);

    // W: this thread stages rows (wave*2+j)*16 + l15, k-chunk kg, j=0..1.
    const unsigned short* wq0 = W + (size_t)((wave * 2 + 0) * 16 + l15) * K + kg * 8;
    const unsigned short* wq1 = W + (size_t)((wave * 2 + 1) * 16 + l15) * K + kg * 8;

    auto STAGE = [&](int buf, int kt) {
        unsigned short* ldsb = &lds[buf][0];
        const int b   = kt >> 3;                    // which 256-col source block
        const int kin = (kt & 7) * 32 + kg * 8;     // element offset within source row
        const char* ap = (b == 0) ? ap0 : (b == 1) ? ap1 : (b == 2) ? ap2 : ap3;
        if ((A.f32mask >> b) & 1) {
            const float* p = (const float*)ap + kin;
            const float4 x = ((const float4*)p)[0];
            const float4 y = ((const float4*)p)[1];
            bfrag8 f;
            f[0] = f2bf16t(x.x); f[1] = f2bf16t(x.y);
            f[2] = f2bf16t(x.z); f[3] = f2bf16t(x.w);
            f[4] = f2bf16t(y.x); f[5] = f2bf16t(y.y);
            f[6] = f2bf16t(y.z); f[7] = f2bf16t(y.w);
            *(bfrag8*)((char*)ldsb + wave * 1024 + lane * 16) = f;
        } else {
            gload_lds16((const unsigned short*)ap + kin, (char*)ldsb + wave * 1024);
        }
        const int koff = kt * 32;
        gload_lds16(wq0 + koff, (char*)ldsb + 8192 + (wave * 2 + 0) * 1024);
        gload_lds16(wq1 + koff, (char*)ldsb + 8192 + (wave * 2 + 1) * 1024);
    };

    accf4 acc[4][4];
    #pragma unroll
    for (int m = 0; m < 4; m++)
        #pragma unroll
        for (int n = 0; n < 4; n++)
            acc[m][n] = (accf4){0.f, 0.f, 0.f, 0.f};

    const int ksteps = A.nblocks * 8;

    STAGE(0, 0);
    __syncthreads();                                // buf0 ready (vmcnt+lgkm drained)

    for (int kt = 0; kt < ksteps; ++kt) {
        const int cur = kt & 1;
        if (kt + 1 < ksteps) STAGE(cur ^ 1, kt + 1);

        const char* ldsb = (const char*)&lds[cur][0];
        bfrag8 af[4], bf[4];
        #pragma unroll
        for (int m = 0; m < 4; m++)
            af[m] = *(const bfrag8*)(ldsb + (wr * 4 + m) * 1024 + lane * 16);
        #pragma unroll
        for (int n = 0; n < 4; n++)
            bf[n] = *(const bfrag8*)(ldsb + 8192 + (wc * 4 + n) * 1024 + lane * 16);
        #pragma unroll
        for (int m = 0; m < 4; m++)
            #pragma unroll
            for (int n = 0; n < 4; n++)
                acc[m][n] = __builtin_amdgcn_mfma_f32_16x16x32_bf16(af[m], bf[n], acc[m][n], 0, 0, 0);

        __syncthreads();   // readers done with buf[cur] + next buf's loads drained
    }

    // epilogue: D fragment (col = l15, row = kg*4 + rg)
    #pragma unroll
    for (int m = 0; m < 4; m++) {
        #pragma unroll
        for (int rg = 0; rg < 4; rg++) {
            const int r = rowbase + wr * 64 + m * 16 + kg * 4 + rg;
            if (r < M) {
                #pragma unroll
                for (int n = 0; n < 4; n++) {
                    const int c = wc * 64 + n * 16 + l15;
                    const size_t off = (size_t)r * HID + c;
                    float v = sspf(acc[m][n][rg]);
                    if (resid) v += resid[off];
                    if (out_f32) ((float*)out)[off] = v;
                    else ((unsigned short*)out)[off] = f2bf(v);
                }
            }
        }
    }
}

__global__ void cvt_w_kernel(const float* __restrict__ src, unsigned short* __restrict__ dst, int n) {
    int i = blockIdx.x * 256 + threadIdx.x;
    if (i < n) dst[i] = f2bf(src[i]);
}

__global__ void be_counts_kernel(const int* __restrict__ src, const int* __restrict__ dst,
                                 const int* __restrict__ batch, int* __restrict__ be,
                                 int* __restrict__ cnt_dst, int* __restrict__ cnt_eg) {
    int e = blockIdx.x * 256 + threadIdx.x;
    if (e < NE) {
        int b = batch[src[e]];
        be[e] = b;
        atomicAdd(&cnt_dst[dst[e]], 1);
        atomicAdd(&cnt_eg[b], 1);
    }
}

__global__ void node_counts_kernel(const int* __restrict__ batch, int* __restrict__ cnt_ng) {
    int i = blockIdx.x * 256 + threadIdx.x;
    if (i < NN) atomicAdd(&cnt_ng[batch[i]], 1);
}

// single-block exclusive prefix scan: rowstart[0..n] from cnt[0..n-1]. 1024 threads.
__global__ void scan_kernel(const int* __restrict__ cnt, int* __restrict__ rowstart, int n) {
    __shared__ int part[1024];
    const int t = threadIdx.x;
    const int chunk = (n + 1023) / 1024;
    const int lo = t * chunk;
    const int hi = (lo + chunk < n) ? lo + chunk : n;
    int s = 0;
    for (int i = lo; i < hi; i++) s += cnt[i];
    part[t] = s;
    __syncthreads();
    for (int d = 1; d < 1024; d <<= 1) {
        int v = (t >= d) ? part[t - d] : 0;
        __syncthreads();
        part[t] += v;
        __syncthreads();
    }
    int base = (t > 0) ? part[t - 1] : 0;
    for (int i = lo; i < hi; i++) { rowstart[i] = base; base += cnt[i]; }
    if (t == 0) rowstart[n] = part[1023];
}

__global__ void fill_csr_kernel(const int* __restrict__ dst, const int* __restrict__ rowstart,
                                int* __restrict__ fill_cnt, int* __restrict__ eids) {
    int e = blockIdx.x * 256 + threadIdx.x;
    if (e < NE) {
        int d = dst[e];
        int pos = rowstart[d] + atomicAdd(&fill_cnt[d], 1);
        eids[pos] = e;
    }
}

// gather-mean of e_mid rows by dst-CSR: one block per node, 256 threads = cols.
__global__ void e2n_mean_kernel(const float* __restrict__ emid, const int* __restrict__ rowstart,
                                const int* __restrict__ eids, unsigned short* __restrict__ out) {
    const int v = blockIdx.x;
    const int c = threadIdx.x;
    const int lo = rowstart[v], hi = rowstart[v + 1];
    float s = 0.f;
    for (int j = lo; j < hi; j++)
        s += emid[(size_t)eids[j] * HID + c];
    const float m = (hi > lo) ? s / (float)(hi - lo) : 0.f;
    out[(size_t)v * HID + c] = f2bf(m);
}

// LDS-binned e2g sum: grid = E2G_CHUNKS x 4 colgroups, block 256 (4 edges x 64 cols).
__global__ void e2g_bin_kernel(const float* __restrict__ emid, const int* __restrict__ be,
                               float* __restrict__ e2g_sum) {
    __shared__ float bins[NG][64];   // 32 KB
    const int cg    = blockIdx.x & 3;
    const int chunk = blockIdx.x >> 2;
    for (int i = threadIdx.x; i < NG * 64; i += 256) ((float*)bins)[i] = 0.f;
    __syncthreads();
    const int per = (NE + E2G_CHUNKS - 1) / E2G_CHUNKS;
    const int lo = chunk * per;
    const int hi = (lo + per < NE) ? lo + per : NE;
    const int esub = threadIdx.x >> 6;
    const int c    = threadIdx.x & 63;
    for (int e0 = lo; e0 < hi; e0 += 4) {
        const int e = e0 + esub;
        if (e < hi) {
            float v = emid[(size_t)e * HID + cg * 64 + c];
            atomicAdd(&bins[be[e]][c], v);
        }
    }
    __syncthreads();
    for (int i = threadIdx.x; i < NG * 64; i += 256) {
        const int g = i >> 6, cc = i & 63;
        const float v = ((float*)bins)[i];
        if (v != 0.f) atomicAdd(&e2g_sum[(size_t)g * HID + cg * 64 + cc], v);
    }
}

// n2g mean: batch is sorted -> contiguous node segments per graph. Block per graph.
__global__ void n2g_mean_kernel(const unsigned short* __restrict__ nmid,
                                const int* __restrict__ noderow,
                                unsigned short* __restrict__ out) {
    const int g = blockIdx.x;
    const int c = threadIdx.x;
    const int lo = noderow[g], hi = noderow[g + 1];
    float s = 0.f;
    for (int i = lo; i < hi; i++)
        s += bf2f(nmid[(size_t)i * HID + c]);
    out[(size_t)g * HID + c] = f2bf((hi > lo) ? s / (float)(hi - lo) : 0.f);
}

__global__ void e2g_mean_kernel(const float* __restrict__ sum, const int* __restrict__ cnt,
                                unsigned short* __restrict__ out) {
    int gid = blockIdx.x * 256 + threadIdx.x;
    if (gid < NG * HID)
        out[gid] = f2bf(sum[gid] / fmaxf((float)cnt[gid >> 8], 1.f));
}

extern "C" void kernel_launch(void* const* d_in, const int* in_sizes, int n_in,
                              void* d_out, int out_size, void* d_ws, size_t ws_size,
                              hipStream_t stream)
{
    (void)in_sizes; (void)n_in; (void)out_size; (void)ws_size;
    const float* node_feats = (const float*)d_in[0];
    const float* edge_feats = (const float*)d_in[1];
    const float* glob_feats = (const float*)d_in[2];
    const int* edge_index   = (const int*)d_in[3];
    const int* batch        = (const int*)d_in[4];
    const float* Wf[9] = {
        (const float*)d_in[5],  (const float*)d_in[6],  (const float*)d_in[7],
        (const float*)d_in[8],  (const float*)d_in[9],  (const float*)d_in[10],
        (const float*)d_in[11], (const float*)d_in[12], (const float*)d_in[13],
    };
    const int Wn[9] = { HID*HID, HID*HID, HID*HID,
                        HID*4*HID, HID*3*HID, HID*3*HID,
                        HID*HID, HID*HID, HID*HID };

    const int* src = edge_index;        // edge_index[0]
    const int* dst = edge_index + NE;   // edge_index[1]

    float* out_n = (float*)d_out;                       // [NN,256] f32
    float* out_e = out_n + (size_t)NN * HID;            // [NE,256] f32
    float* out_g = out_e + (size_t)NE * HID;            // [NG,256] f32

    // ws layout. Zero-init region first -> single memsetAsync (~0.3 MB).
    char* ws = (char*)d_ws;
    size_t off = 0;
    auto alloc = [&](size_t bytes) -> char* {
        char* p = ws + off; off += (bytes + 255) & ~(size_t)255; return p;
    };
    float* e2g_sum = (float*)alloc((size_t)NG * HID * 4);
    int* cnt_dst   = (int*)alloc((size_t)NN * 4);
    int* fill_cnt  = (int*)alloc((size_t)NN * 4);
    int* cnt_eg    = (int*)alloc((size_t)NG * 4);
    int* cnt_ng    = (int*)alloc((size_t)NG * 4);
    size_t zero_bytes = off;
    hipMemsetAsync(d_ws, 0, zero_bytes, stream);

    int* rowstart_dst        = (int*)alloc((size_t)(NN + 1) * 4);
    int* noderow             = (int*)alloc((size_t)(NG + 1) * 4);
    int* eids                = (int*)alloc((size_t)NE * 4);
    int* be                  = (int*)alloc((size_t)NE * 4);
    unsigned short* n1       = (unsigned short*)alloc((size_t)NN * HID * 2);
    unsigned short* g1       = (unsigned short*)alloc((size_t)NG * HID * 2);
    unsigned short* e2n_mean = (unsigned short*)alloc((size_t)NN * HID * 2);
    unsigned short* n_mid    = (unsigned short*)alloc((size_t)NN * HID * 2);
    unsigned short* n2g_mean = (unsigned short*)alloc((size_t)NG * HID * 2);
    unsigned short* e2g_mean = (unsigned short*)alloc((size_t)NG * HID * 2);
    unsigned short* g_mid    = (unsigned short*)alloc((size_t)NG * HID * 2);
    unsigned short* Wb[9];
    for (int i = 0; i < 9; i++) Wb[i] = (unsigned short*)alloc((size_t)Wn[i] * 2);

    // Aliases into d_out:
    float* e1    = out_e;   // stage-1 edge activations, f32, in place
    float* e_mid = out_e;   // edge-MLP output, f32, in place (identity rows)

    // weights -> bf16 (9 tiny launches, 1M elements total)
    for (int i = 0; i < 9; i++)
        cvt_w_kernel<<<(Wn[i] + 255) / 256, 256, 0, stream>>>(Wf[i], Wb[i], Wn[i]);

    // graph/CSR setup (all tiny)
    be_counts_kernel<<<(NE + 255) / 256, 256, 0, stream>>>(src, dst, batch, be, cnt_dst, cnt_eg);
    node_counts_kernel<<<(NN + 255) / 256, 256, 0, stream>>>(batch, cnt_ng);
    scan_kernel<<<1, 1024, 0, stream>>>(cnt_dst, rowstart_dst, NN);
    scan_kernel<<<1, 1024, 0, stream>>>(cnt_ng, noderow, NG);
    fill_csr_kernel<<<(NE + 255) / 256, 256, 0, stream>>>(dst, rowstart_dst, fill_cnt, eids);

    auto launch_gemm = [&](const ASpec& A, const unsigned short* W,
                           void* o, int of32, const float* resid, int M) {
        gemm_ssp_kernel<<<(M + 127) / 128, 512, 0, stream>>>(A, W, o, of32, resid, M);
    };

    // stage 1: lin_*_1 + ssp
    { ASpec a{}; a.base[0] = node_feats; a.f32mask = 1; a.nblocks = 1;
      launch_gemm(a, Wb[0], n1, 0, nullptr, NN); }
    { ASpec a{}; a.base[0] = edge_feats; a.f32mask = 1; a.nblocks = 1;
      launch_gemm(a, Wb[1], e1, 1, nullptr, NE); }
    { ASpec a{}; a.base[0] = glob_feats; a.f32mask = 1; a.nblocks = 1;
      launch_gemm(a, Wb[2], g1, 0, nullptr, NG); }

    // EdgeModel: gather-concat fused into A-load, K=1024 (in place on out_e)
    { ASpec a{};
      a.base[0] = n1; a.idx[0] = src;
      a.base[1] = n1; a.idx[1] = dst;
      a.base[2] = e1; a.idx[2] = nullptr;
      a.base[3] = g1; a.idx[3] = be;
      a.f32mask = 0b0100;   // block 2 (e1) is f32
      a.nblocks = 4;
      launch_gemm(a, Wb[3], e_mid, 1, nullptr, NE); }

    // scatter-means via gather / LDS bins (no bulk global atomics)
    e2n_mean_kernel<<<NN, 256, 0, stream>>>(e_mid, rowstart_dst, eids, e2n_mean);
    e2g_bin_kernel<<<E2G_CHUNKS * 4, 256, 0, stream>>>(e_mid, be, e2g_sum);
    e2g_mean_kernel<<<(NG * HID + 255) / 256, 256, 0, stream>>>(e2g_sum, cnt_eg, e2g_mean);

    // NodeModel: K=768 -> n_mid bf16 (all-bf16 A: fast gload_lds path)
    { ASpec a{};
      a.base[0] = n1;
      a.base[1] = e2n_mean;
      a.base[2] = g1; a.idx[2] = batch;
      a.f32mask = 0; a.nblocks = 3;
      launch_gemm(a, Wb[4], n_mid, 0, nullptr, NN); }

    // nodes -> graphs mean (batch sorted -> contiguous segments, no atomics)
    n2g_mean_kernel<<<NG, 256, 0, stream>>>(n_mid, noderow, n2g_mean);

    // GlobalModel: K=768 -> g_mid bf16
    { ASpec a{};
      a.base[0] = n2g_mean; a.base[1] = e2g_mean; a.base[2] = g1;
      a.f32mask = 0; a.nblocks = 3;
      launch_gemm(a, Wb[5], g_mid, 0, nullptr, NG); }

    // final lin_*_2 + ssp + residual -> f32 d_out (edge runs in place on out_e)
    { ASpec a{}; a.base[0] = n_mid; a.f32mask = 0; a.nblocks = 1;
      launch_gemm(a, Wb[6], out_n, 1, node_feats, NN); }
    { ASpec a{}; a.base[0] = e_mid; a.f32mask = 1; a.nblocks = 1;
      launch_gemm(a, Wb[7], out_e, 1, edge_feats, NE); }
    { ASpec a{}; a.base[0] = g_mid; a.f32mask = 0; a.nblocks = 1;
      launch_gemm(a, Wb[8], out_g, 1, glob_feats, NG); }
}

// Round 5
// 2440.980 us; speedup vs baseline: 1.3448x; 1.2739x over previous
//
#include <hip/hip_runtime.h>
#include <hip/hip_bf16.h>
#include <cstdint>
#include <cstddef>

#define NN 20000
#define NE 200000
#define NG 128
#define HID 256
#define E2G_CHUNKS 64   // edge chunks for the LDS-binned e2g reduction

typedef __bf16 bfrag8 __attribute__((ext_vector_type(8)));  // 8 bf16 (4 VGPRs)
typedef float  accf4  __attribute__((ext_vector_type(4)));  // 4 fp32 acc

__device__ __forceinline__ unsigned short f2bf(float f) {
    union { float f; unsigned int i; } x; x.f = f;
    unsigned int r = x.i + 0x7fffu + ((x.i >> 16) & 1u);  // RNE
    return (unsigned short)(r >> 16);
}
__device__ __forceinline__ __bf16 f2bf16t(float f) {
    union { unsigned short u; __bf16 b; } x; x.u = f2bf(f); return x.b;
}
__device__ __forceinline__ float bf2f(unsigned short u) {
    union { unsigned int i; float f; } x; x.i = ((unsigned int)u) << 16; return x.f;
}
__device__ __forceinline__ float sspf(float x) {
    // softplus(x) - log(2), numerically stable
    return fmaxf(x, 0.f) + log1pf(expf(-fabsf(x))) - 0.69314718055994530942f;
}

// async 16B global -> LDS (per-lane global addr, lane-linear LDS dest: base + lane*16)
__device__ __forceinline__ void gload_lds16(const void* g, void* l) {
    __builtin_amdgcn_global_load_lds(
        (const __attribute__((address_space(1))) unsigned int*)g,
        (__attribute__((address_space(3))) unsigned int*)l,
        16, 0, 0);
}

// A-operand spec: virtual A[M, nblocks*256] = concat of up to 4 [.,256] sources,
// each with optional row-index indirection (nullptr => identity) and a per-block
// dtype flag (f32mask bit b set => base[b] is const float*, else bf16).
struct ASpec {
    const void* base[4];
    const int* idx[4];
    int f32mask;
    int nblocks;
};

// out[M,256] = ssp( A_virtual[M,K] @ Wbf16[256,K]^T ) (+ resid_f32), out f32 or bf16.
//
// LDS-staged MFMA GEMM, tile = 128 rows x 256 cols, 8 waves (2 row-groups x 4
// col-groups), K-step 32. LDS/buf: A 128x32 (8 x 1KB subtiles) + W 256x32 (16
// subtiles) = 24KB, double-buffered = 48KB. Fragment-ordered layout (subtile base +
// lane*16): linear, conflict-free ds_read_b128, matches global_load_lds' lane-linear
// destination. Wave w stages A-subtile w (rows w*16..w*16+15, per-lane gather
// addresses ok) and W-subtiles 2w, 2w+1. f32 A-sources: VGPR convert + ds_write.
//
// REGISTER BUDGET (r4 lesson): __launch_bounds__(512,6) capped unified VGPR at ~85;
// acc[4][4]=64 AGPR + frags + addressing needs ~120-130 -> compiler spilled to
// scratch -> 2.3 GB of HBM RMW traffic (VGPR_Count=40, WRITE>FETCH signature).
// Now (512,4): cap 128, 2 blocks/CU = 16 waves/CU. B-fragments loaded one-per-n
// to keep live regs ~120 < 128. NO spill is the top priority here.
//
// NOTE (r2 lesson): no global atomics in the epilogue — device-scope f32 atomics
// execute memory-side (past per-XCD L2) and ballooned HBM traffic 0.76 -> 3.7 GB.
//
// In-place safe when out aliases an identity-indexed A block: each block reads only
// its own 128 rows; all global A reads are drained by the barrier after their STAGE;
// clamped tail rows never store (r < M guard).
__global__ __launch_bounds__(512, 4) void gemm_ssp_kernel(
    ASpec A, const unsigned short* __restrict__ W,
    void* __restrict__ out, int out_f32,
    const float* __restrict__ resid, int M)
{
    __shared__ unsigned short lds[2][12288];   // 2 x 24KB: [A: 8*512 | W: 16*512] shorts

    const int K    = A.nblocks * HID;
    const int lane = threadIdx.x & 63;
    const int wave = threadIdx.x >> 6;
    const int l15  = lane & 15;
    const int kg   = lane >> 4;
    const int wr   = wave >> 2;      // row-group 0..1
    const int wc   = wave & 3;       // col-group 0..3
    const int rowbase = blockIdx.x * 128;

    // ---- staging setup: per-thread fixed source pointers ----
    const int arow = rowbase + wave * 16 + l15;
    const int arc  = arow < M ? arow : (M - 1);
    auto mkap = [&](int b) -> const char* {
        if (b >= A.nblocks) return (const char*)A.base[0];
        const int rid = A.idx[b] ? A.idx[b][arc] : arc;
        const int e4 = (A.f32mask >> b) & 1;
        return (const char*)A.base[b] + (size_t)rid * (size_t)(HID * (e4 ? 4 : 2));
    };
    const char* ap0 = mkap(0);
    const char* ap1 = mkap(1);
    const char* ap2 = mkap(2);
    const char* ap3 = mkap(3);

    // W: this thread stages rows (wave*2+j)*16 + l15, k-chunk kg, j=0..1.
    const unsigned short* wq0 = W + (size_t)((wave * 2 + 0) * 16 + l15) * K + kg * 8;
    const unsigned short* wq1 = W + (size_t)((wave * 2 + 1) * 16 + l15) * K + kg * 8;

    auto STAGE = [&](int buf, int kt) {
        unsigned short* ldsb = &lds[buf][0];
        const int b   = kt >> 3;                    // which 256-col source block
        const int kin = (kt & 7) * 32 + kg * 8;     // element offset within source row
        const char* ap = (b == 0) ? ap0 : (b == 1) ? ap1 : (b == 2) ? ap2 : ap3;
        if ((A.f32mask >> b) & 1) {
            const float* p = (const float*)ap + kin;
            const float4 x = ((const float4*)p)[0];
            const float4 y = ((const float4*)p)[1];
            bfrag8 f;
            f[0] = f2bf16t(x.x); f[1] = f2bf16t(x.y);
            f[2] = f2bf16t(x.z); f[3] = f2bf16t(x.w);
            f[4] = f2bf16t(y.x); f[5] = f2bf16t(y.y);
            f[6] = f2bf16t(y.z); f[7] = f2bf16t(y.w);
            *(bfrag8*)((char*)ldsb + wave * 1024 + lane * 16) = f;
        } else {
            gload_lds16((const unsigned short*)ap + kin, (char*)ldsb + wave * 1024);
        }
        const int koff = kt * 32;
        gload_lds16(wq0 + koff, (char*)ldsb + 8192 + (wave * 2 + 0) * 1024);
        gload_lds16(wq1 + koff, (char*)ldsb + 8192 + (wave * 2 + 1) * 1024);
    };

    accf4 acc[4][4];
    #pragma unroll
    for (int m = 0; m < 4; m++)
        #pragma unroll
        for (int n = 0; n < 4; n++)
            acc[m][n] = (accf4){0.f, 0.f, 0.f, 0.f};

    const int ksteps = A.nblocks * 8;

    STAGE(0, 0);
    __syncthreads();                                // buf0 ready (vmcnt+lgkm drained)

    for (int kt = 0; kt < ksteps; ++kt) {
        const int cur = kt & 1;
        if (kt + 1 < ksteps) STAGE(cur ^ 1, kt + 1);

        const char* ldsb = (const char*)&lds[cur][0];
        // A-fragments for this wave's 4 row-tiles (16 VGPRs, live across the n-loop)
        const bfrag8 af0 = *(const bfrag8*)(ldsb + (wr * 4 + 0) * 1024 + lane * 16);
        const bfrag8 af1 = *(const bfrag8*)(ldsb + (wr * 4 + 1) * 1024 + lane * 16);
        const bfrag8 af2 = *(const bfrag8*)(ldsb + (wr * 4 + 2) * 1024 + lane * 16);
        const bfrag8 af3 = *(const bfrag8*)(ldsb + (wr * 4 + 3) * 1024 + lane * 16);
        // B-fragments one at a time (4 VGPRs live) to stay under the 128-reg cap
        #pragma unroll
        for (int n = 0; n < 4; n++) {
            const bfrag8 bfn = *(const bfrag8*)(ldsb + 8192 + (wc * 4 + n) * 1024 + lane * 16);
            acc[0][n] = __builtin_amdgcn_mfma_f32_16x16x32_bf16(af0, bfn, acc[0][n], 0, 0, 0);
            acc[1][n] = __builtin_amdgcn_mfma_f32_16x16x32_bf16(af1, bfn, acc[1][n], 0, 0, 0);
            acc[2][n] = __builtin_amdgcn_mfma_f32_16x16x32_bf16(af2, bfn, acc[2][n], 0, 0, 0);
            acc[3][n] = __builtin_amdgcn_mfma_f32_16x16x32_bf16(af3, bfn, acc[3][n], 0, 0, 0);
        }

        __syncthreads();   // readers done with buf[cur] + next buf's loads drained
    }

    // epilogue: D fragment (col = l15, row = kg*4 + rg)
    #pragma unroll
    for (int m = 0; m < 4; m++) {
        #pragma unroll
        for (int rg = 0; rg < 4; rg++) {
            const int r = rowbase + wr * 64 + m * 16 + kg * 4 + rg;
            if (r < M) {
                #pragma unroll
                for (int n = 0; n < 4; n++) {
                    const int c = wc * 64 + n * 16 + l15;
                    const size_t off = (size_t)r * HID + c;
                    float v = sspf(acc[m][n][rg]);
                    if (resid) v += resid[off];
                    if (out_f32) ((float*)out)[off] = v;
                    else ((unsigned short*)out)[off] = f2bf(v);
                }
            }
        }
    }
}

__global__ void cvt_w_kernel(const float* __restrict__ src, unsigned short* __restrict__ dst, int n) {
    int i = blockIdx.x * 256 + threadIdx.x;
    if (i < n) dst[i] = f2bf(src[i]);
}

__global__ void be_counts_kernel(const int* __restrict__ src, const int* __restrict__ dst,
                                 const int* __restrict__ batch, int* __restrict__ be,
                                 int* __restrict__ cnt_dst, int* __restrict__ cnt_eg) {
    int e = blockIdx.x * 256 + threadIdx.x;
    if (e < NE) {
        int b = batch[src[e]];
        be[e] = b;
        atomicAdd(&cnt_dst[dst[e]], 1);
        atomicAdd(&cnt_eg[b], 1);
    }
}

__global__ void node_counts_kernel(const int* __restrict__ batch, int* __restrict__ cnt_ng) {
    int i = blockIdx.x * 256 + threadIdx.x;
    if (i < NN) atomicAdd(&cnt_ng[batch[i]], 1);
}

// single-block exclusive prefix scan: rowstart[0..n] from cnt[0..n-1]. 1024 threads.
__global__ void scan_kernel(const int* __restrict__ cnt, int* __restrict__ rowstart, int n) {
    __shared__ int part[1024];
    const int t = threadIdx.x;
    const int chunk = (n + 1023) / 1024;
    const int lo = t * chunk;
    const int hi = (lo + chunk < n) ? lo + chunk : n;
    int s = 0;
    for (int i = lo; i < hi; i++) s += cnt[i];
    part[t] = s;
    __syncthreads();
    for (int d = 1; d < 1024; d <<= 1) {
        int v = (t >= d) ? part[t - d] : 0;
        __syncthreads();
        part[t] += v;
        __syncthreads();
    }
    int base = (t > 0) ? part[t - 1] : 0;
    for (int i = lo; i < hi; i++) { rowstart[i] = base; base += cnt[i]; }
    if (t == 0) rowstart[n] = part[1023];
}

__global__ void fill_csr_kernel(const int* __restrict__ dst, const int* __restrict__ rowstart,
                                int* __restrict__ fill_cnt, int* __restrict__ eids) {
    int e = blockIdx.x * 256 + threadIdx.x;
    if (e < NE) {
        int d = dst[e];
        int pos = rowstart[d] + atomicAdd(&fill_cnt[d], 1);
        eids[pos] = e;
    }
}

// gather-mean of e_mid rows by dst-CSR: one block per node, 256 threads = cols.
__global__ void e2n_mean_kernel(const float* __restrict__ emid, const int* __restrict__ rowstart,
                                const int* __restrict__ eids, unsigned short* __restrict__ out) {
    const int v = blockIdx.x;
    const int c = threadIdx.x;
    const int lo = rowstart[v], hi = rowstart[v + 1];
    float s = 0.f;
    for (int j = lo; j < hi; j++)
        s += emid[(size_t)eids[j] * HID + c];
    const float m = (hi > lo) ? s / (float)(hi - lo) : 0.f;
    out[(size_t)v * HID + c] = f2bf(m);
}

// LDS-binned e2g sum: grid = E2G_CHUNKS x 4 colgroups, block 256 (4 edges x 64 cols).
__global__ void e2g_bin_kernel(const float* __restrict__ emid, const int* __restrict__ be,
                               float* __restrict__ e2g_sum) {
    __shared__ float bins[NG][64];   // 32 KB
    const int cg    = blockIdx.x & 3;
    const int chunk = blockIdx.x >> 2;
    for (int i = threadIdx.x; i < NG * 64; i += 256) ((float*)bins)[i] = 0.f;
    __syncthreads();
    const int per = (NE + E2G_CHUNKS - 1) / E2G_CHUNKS;
    const int lo = chunk * per;
    const int hi = (lo + per < NE) ? lo + per : NE;
    const int esub = threadIdx.x >> 6;
    const int c    = threadIdx.x & 63;
    for (int e0 = lo; e0 < hi; e0 += 4) {
        const int e = e0 + esub;
        if (e < hi) {
            float v = emid[(size_t)e * HID + cg * 64 + c];
            atomicAdd(&bins[be[e]][c], v);
        }
    }
    __syncthreads();
    for (int i = threadIdx.x; i < NG * 64; i += 256) {
        const int g = i >> 6, cc = i & 63;
        const float v = ((float*)bins)[i];
        if (v != 0.f) atomicAdd(&e2g_sum[(size_t)g * HID + cg * 64 + cc], v);
    }
}

// n2g mean: batch is sorted -> contiguous node segments per graph. Block per graph.
__global__ void n2g_mean_kernel(const unsigned short* __restrict__ nmid,
                                const int* __restrict__ noderow,
                                unsigned short* __restrict__ out) {
    const int g = blockIdx.x;
    const int c = threadIdx.x;
    const int lo = noderow[g], hi = noderow[g + 1];
    float s = 0.f;
    for (int i = lo; i < hi; i++)
        s += bf2f(nmid[(size_t)i * HID + c]);
    out[(size_t)g * HID + c] = f2bf((hi > lo) ? s / (float)(hi - lo) : 0.f);
}

__global__ void e2g_mean_kernel(const float* __restrict__ sum, const int* __restrict__ cnt,
                                unsigned short* __restrict__ out) {
    int gid = blockIdx.x * 256 + threadIdx.x;
    if (gid < NG * HID)
        out[gid] = f2bf(sum[gid] / fmaxf((float)cnt[gid >> 8], 1.f));
}

extern "C" void kernel_launch(void* const* d_in, const int* in_sizes, int n_in,
                              void* d_out, int out_size, void* d_ws, size_t ws_size,
                              hipStream_t stream)
{
    (void)in_sizes; (void)n_in; (void)out_size; (void)ws_size;
    const float* node_feats = (const float*)d_in[0];
    const float* edge_feats = (const float*)d_in[1];
    const float* glob_feats = (const float*)d_in[2];
    const int* edge_index   = (const int*)d_in[3];
    const int* batch        = (const int*)d_in[4];
    const float* Wf[9] = {
        (const float*)d_in[5],  (const float*)d_in[6],  (const float*)d_in[7],
        (const float*)d_in[8],  (const float*)d_in[9],  (const float*)d_in[10],
        (const float*)d_in[11], (const float*)d_in[12], (const float*)d_in[13],
    };
    const int Wn[9] = { HID*HID, HID*HID, HID*HID,
                        HID*4*HID, HID*3*HID, HID*3*HID,
                        HID*HID, HID*HID, HID*HID };

    const int* src = edge_index;        // edge_index[0]
    const int* dst = edge_index + NE;   // edge_index[1]

    float* out_n = (float*)d_out;                       // [NN,256] f32
    float* out_e = out_n + (size_t)NN * HID;            // [NE,256] f32
    float* out_g = out_e + (size_t)NE * HID;            // [NG,256] f32

    // ws layout. Zero-init region first -> single memsetAsync (~0.3 MB).
    char* ws = (char*)d_ws;
    size_t off = 0;
    auto alloc = [&](size_t bytes) -> char* {
        char* p = ws + off; off += (bytes + 255) & ~(size_t)255; return p;
    };
    float* e2g_sum = (float*)alloc((size_t)NG * HID * 4);
    int* cnt_dst   = (int*)alloc((size_t)NN * 4);
    int* fill_cnt  = (int*)alloc((size_t)NN * 4);
    int* cnt_eg    = (int*)alloc((size_t)NG * 4);
    int* cnt_ng    = (int*)alloc((size_t)NG * 4);
    size_t zero_bytes = off;
    hipMemsetAsync(d_ws, 0, zero_bytes, stream);

    int* rowstart_dst        = (int*)alloc((size_t)(NN + 1) * 4);
    int* noderow             = (int*)alloc((size_t)(NG + 1) * 4);
    int* eids                = (int*)alloc((size_t)NE * 4);
    int* be                  = (int*)alloc((size_t)NE * 4);
    unsigned short* n1       = (unsigned short*)alloc((size_t)NN * HID * 2);
    unsigned short* g1       = (unsigned short*)alloc((size_t)NG * HID * 2);
    unsigned short* e2n_mean = (unsigned short*)alloc((size_t)NN * HID * 2);
    unsigned short* n_mid    = (unsigned short*)alloc((size_t)NN * HID * 2);
    unsigned short* n2g_mean = (unsigned short*)alloc((size_t)NG * HID * 2);
    unsigned short* e2g_mean = (unsigned short*)alloc((size_t)NG * HID * 2);
    unsigned short* g_mid    = (unsigned short*)alloc((size_t)NG * HID * 2);
    unsigned short* Wb[9];
    for (int i = 0; i < 9; i++) Wb[i] = (unsigned short*)alloc((size_t)Wn[i] * 2);

    // Aliases into d_out:
    float* e1    = out_e;   // stage-1 edge activations, f32, in place
    float* e_mid = out_e;   // edge-MLP output, f32, in place (identity rows)

    // weights -> bf16 (9 tiny launches, 1M elements total)
    for (int i = 0; i < 9; i++)
        cvt_w_kernel<<<(Wn[i] + 255) / 256, 256, 0, stream>>>(Wf[i], Wb[i], Wn[i]);

    // graph/CSR setup (all tiny)
    be_counts_kernel<<<(NE + 255) / 256, 256, 0, stream>>>(src, dst, batch, be, cnt_dst, cnt_eg);
    node_counts_kernel<<<(NN + 255) / 256, 256, 0, stream>>>(batch, cnt_ng);
    scan_kernel<<<1, 1024, 0, stream>>>(cnt_dst, rowstart_dst, NN);
    scan_kernel<<<1, 1024, 0, stream>>>(cnt_ng, noderow, NG);
    fill_csr_kernel<<<(NE + 255) / 256, 256, 0, stream>>>(dst, rowstart_dst, fill_cnt, eids);

    auto launch_gemm = [&](const ASpec& A, const unsigned short* W,
                           void* o, int of32, const float* resid, int M) {
        gemm_ssp_kernel<<<(M + 127) / 128, 512, 0, stream>>>(A, W, o, of32, resid, M);
    };

    // stage 1: lin_*_1 + ssp
    { ASpec a{}; a.base[0] = node_feats; a.f32mask = 1; a.nblocks = 1;
      launch_gemm(a, Wb[0], n1, 0, nullptr, NN); }
    { ASpec a{}; a.base[0] = edge_feats; a.f32mask = 1; a.nblocks = 1;
      launch_gemm(a, Wb[1], e1, 1, nullptr, NE); }
    { ASpec a{}; a.base[0] = glob_feats; a.f32mask = 1; a.nblocks = 1;
      launch_gemm(a, Wb[2], g1, 0, nullptr, NG); }

    // EdgeModel: gather-concat fused into A-load, K=1024 (in place on out_e)
    { ASpec a{};
      a.base[0] = n1; a.idx[0] = src;
      a.base[1] = n1; a.idx[1] = dst;
      a.base[2] = e1; a.idx[2] = nullptr;
      a.base[3] = g1; a.idx[3] = be;
      a.f32mask = 0b0100;   // block 2 (e1) is f32
      a.nblocks = 4;
      launch_gemm(a, Wb[3], e_mid, 1, nullptr, NE); }

    // scatter-means via gather / LDS bins (no bulk global atomics)
    e2n_mean_kernel<<<NN, 256, 0, stream>>>(e_mid, rowstart_dst, eids, e2n_mean);
    e2g_bin_kernel<<<E2G_CHUNKS * 4, 256, 0, stream>>>(e_mid, be, e2g_sum);
    e2g_mean_kernel<<<(NG * HID + 255) / 256, 256, 0, stream>>>(e2g_sum, cnt_eg, e2g_mean);

    // NodeModel: K=768 -> n_mid bf16 (all-bf16 A: fast gload_lds path)
    { ASpec a{};
      a.base[0] = n1;
      a.base[1] = e2n_mean;
      a.base[2] = g1; a.idx[2] = batch;
      a.f32mask = 0; a.nblocks = 3;
      launch_gemm(a, Wb[4], n_mid, 0, nullptr, NN); }

    // nodes -> graphs mean (batch sorted -> contiguous segments, no atomics)
    n2g_mean_kernel<<<NG, 256, 0, stream>>>(n_mid, noderow, n2g_mean);

    // GlobalModel: K=768 -> g_mid bf16
    { ASpec a{};
      a.base[0] = n2g_mean; a.base[1] = e2g_mean; a.base[2] = g1;
      a.f32mask = 0; a.nblocks = 3;
      launch_gemm(a, Wb[5], g_mid, 0, nullptr, NG); }

    // final lin_*_2 + ssp + residual -> f32 d_out (edge runs in place on out_e)
    { ASpec a{}; a.base[0] = n_mid; a.f32mask = 0; a.nblocks = 1;
      launch_gemm(a, Wb[6], out_n, 1, node_feats, NN); }
    { ASpec a{}; a.base[0] = e_mid; a.f32mask = 1; a.nblocks = 1;
      launch_gemm(a, Wb[7], out_e, 1, edge_feats, NE); }
    { ASpec a{}; a.base[0] = g_mid; a.f32mask = 0; a.nblocks = 1;
      launch_gemm(a, Wb[8], out_g, 1, glob_feats, NG); }
}

// Round 6
// 1909.396 us; speedup vs baseline: 1.7192x; 1.2784x over previous
//
#include <hip/hip_runtime.h>
#include <hip/hip_bf16.h>
#include <cstdint>
#include <cstddef>

#define NN 20000
#define NE 200000
#define NG 128
#define HID 256
#define E2G_CHUNKS 64   // edge chunks for the LDS-binned e2g reduction

typedef __bf16 bfrag8 __attribute__((ext_vector_type(8)));  // 8 bf16 (4 VGPRs)
typedef float  accf4  __attribute__((ext_vector_type(4)));  // 4 fp32 acc

__device__ __forceinline__ unsigned short f2bf(float f) {
    union { float f; unsigned int i; } x; x.f = f;
    unsigned int r = x.i + 0x7fffu + ((x.i >> 16) & 1u);  // RNE
    return (unsigned short)(r >> 16);
}
__device__ __forceinline__ __bf16 f2bf16t(float f) {
    union { unsigned short u; __bf16 b; } x; x.u = f2bf(f); return x.b;
}
__device__ __forceinline__ float bf2f(unsigned short u) {
    union { unsigned int i; float f; } x; x.i = ((unsigned int)u) << 16; return x.f;
}
// softplus(x) - log(2) via HW transcendentals (v_exp_f32/v_log_f32, ~7 insts).
// r5 lesson: libm log1pf/expf cost ~40+ VALU insts; 64 calls/thread made the
// GEMM epilogue VALU-bound (VALUBusy 42%). Abs error ~1e-6 << bf16 noise floor.
__device__ __forceinline__ float sspf(float x) {
    float e = __expf(-fabsf(x));
    return fmaxf(x, 0.f) + __logf(1.f + e) - 0.69314718055994530942f;
}

// async 16B global -> LDS (per-lane global addr, lane-linear LDS dest: base + lane*16)
__device__ __forceinline__ void gload_lds16(const void* g, void* l) {
    __builtin_amdgcn_global_load_lds(
        (const __attribute__((address_space(1))) unsigned int*)g,
        (__attribute__((address_space(3))) unsigned int*)l,
        16, 0, 0);
}

// A-operand spec: virtual A[M, nblocks*256] = concat of up to 4 [.,256] sources,
// each with optional row-index indirection (nullptr => identity) and a per-block
// dtype flag (f32mask bit b set => base[b] is const float*, else bf16).
struct ASpec {
    const void* base[4];
    const int* idx[4];
    int f32mask;
    int nblocks;
};

// ---------------------------------------------------------------------------
// Generic GEMM (supports f32 A-blocks): 2-barrier double-buffered structure.
// tile = 128x256, 8 waves, K-step 32, LDS 2x24KB. Used for stage-1 (f32 inputs)
// and as fallback when ws is too small for the bf16 e-stream.
// Reg budget (r4 lesson): (512,4) -> cap 128; acc in AGPR (64) + ~60 VGPR, no spill.
// r2 lesson: no global atomics in epilogues.
// ---------------------------------------------------------------------------
__global__ __launch_bounds__(512, 4) void gemm_ssp_kernel(
    ASpec A, const unsigned short* __restrict__ W,
    void* __restrict__ out, int out_f32,
    const float* __restrict__ resid, int M)
{
    __shared__ unsigned short lds[2][12288];   // 2 x 24KB: [A: 8*512 | W: 16*512] shorts

    const int K    = A.nblocks * HID;
    const int lane = threadIdx.x & 63;
    const int wave = threadIdx.x >> 6;
    const int l15  = lane & 15;
    const int kg   = lane >> 4;
    const int wr   = wave >> 2;      // row-group 0..1
    const int wc   = wave & 3;       // col-group 0..3
    const int rowbase = blockIdx.x * 128;

    const int arow = rowbase + wave * 16 + l15;
    const int arc  = arow < M ? arow : (M - 1);
    auto mkap = [&](int b) -> const char* {
        if (b >= A.nblocks) return (const char*)A.base[0];
        const int rid = A.idx[b] ? A.idx[b][arc] : arc;
        const int e4 = (A.f32mask >> b) & 1;
        return (const char*)A.base[b] + (size_t)rid * (size_t)(HID * (e4 ? 4 : 2));
    };
    const char* ap0 = mkap(0);
    const char* ap1 = mkap(1);
    const char* ap2 = mkap(2);
    const char* ap3 = mkap(3);

    const unsigned short* wq0 = W + (size_t)((wave * 2 + 0) * 16 + l15) * K + kg * 8;
    const unsigned short* wq1 = W + (size_t)((wave * 2 + 1) * 16 + l15) * K + kg * 8;

    auto STAGE = [&](int buf, int kt) {
        unsigned short* ldsb = &lds[buf][0];
        const int b   = kt >> 3;
        const int kin = (kt & 7) * 32 + kg * 8;
        const char* ap = (b == 0) ? ap0 : (b == 1) ? ap1 : (b == 2) ? ap2 : ap3;
        if ((A.f32mask >> b) & 1) {
            const float* p = (const float*)ap + kin;
            const float4 x = ((const float4*)p)[0];
            const float4 y = ((const float4*)p)[1];
            bfrag8 f;
            f[0] = f2bf16t(x.x); f[1] = f2bf16t(x.y);
            f[2] = f2bf16t(x.z); f[3] = f2bf16t(x.w);
            f[4] = f2bf16t(y.x); f[5] = f2bf16t(y.y);
            f[6] = f2bf16t(y.z); f[7] = f2bf16t(y.w);
            *(bfrag8*)((char*)ldsb + wave * 1024 + lane * 16) = f;
        } else {
            gload_lds16((const unsigned short*)ap + kin, (char*)ldsb + wave * 1024);
        }
        const int koff = kt * 32;
        gload_lds16(wq0 + koff, (char*)ldsb + 8192 + (wave * 2 + 0) * 1024);
        gload_lds16(wq1 + koff, (char*)ldsb + 8192 + (wave * 2 + 1) * 1024);
    };

    accf4 acc[4][4];
    #pragma unroll
    for (int m = 0; m < 4; m++)
        #pragma unroll
        for (int n = 0; n < 4; n++)
            acc[m][n] = (accf4){0.f, 0.f, 0.f, 0.f};

    const int ksteps = A.nblocks * 8;

    STAGE(0, 0);
    __syncthreads();

    for (int kt = 0; kt < ksteps; ++kt) {
        const int cur = kt & 1;
        if (kt + 1 < ksteps) STAGE(cur ^ 1, kt + 1);

        const char* ldsb = (const char*)&lds[cur][0];
        const bfrag8 af0 = *(const bfrag8*)(ldsb + (wr * 4 + 0) * 1024 + lane * 16);
        const bfrag8 af1 = *(const bfrag8*)(ldsb + (wr * 4 + 1) * 1024 + lane * 16);
        const bfrag8 af2 = *(const bfrag8*)(ldsb + (wr * 4 + 2) * 1024 + lane * 16);
        const bfrag8 af3 = *(const bfrag8*)(ldsb + (wr * 4 + 3) * 1024 + lane * 16);
        #pragma unroll
        for (int n = 0; n < 4; n++) {
            const bfrag8 bfn = *(const bfrag8*)(ldsb + 8192 + (wc * 4 + n) * 1024 + lane * 16);
            acc[0][n] = __builtin_amdgcn_mfma_f32_16x16x32_bf16(af0, bfn, acc[0][n], 0, 0, 0);
            acc[1][n] = __builtin_amdgcn_mfma_f32_16x16x32_bf16(af1, bfn, acc[1][n], 0, 0, 0);
            acc[2][n] = __builtin_amdgcn_mfma_f32_16x16x32_bf16(af2, bfn, acc[2][n], 0, 0, 0);
            acc[3][n] = __builtin_amdgcn_mfma_f32_16x16x32_bf16(af3, bfn, acc[3][n], 0, 0, 0);
        }

        __syncthreads();
    }

    #pragma unroll
    for (int m = 0; m < 4; m++) {
        #pragma unroll
        for (int rg = 0; rg < 4; rg++) {
            const int r = rowbase + wr * 64 + m * 16 + kg * 4 + rg;
            if (r < M) {
                #pragma unroll
                for (int n = 0; n < 4; n++) {
                    const int c = wc * 64 + n * 16 + l15;
                    const size_t off = (size_t)r * HID + c;
                    float v = sspf(acc[m][n][rg]);
                    if (resid) v += resid[off];
                    if (out_f32) ((float*)out)[off] = v;
                    else ((unsigned short*)out)[off] = f2bf(v);
                }
            }
        }
    }
}

// ---------------------------------------------------------------------------
// All-bf16-A pipelined GEMM (T3/T4): triple-buffered LDS (3x24KB), depth-2
// prefetch, counted s_waitcnt vmcnt + raw s_barrier so prefetch loads stay in
// flight ACROSS barriers (never drain to 0 mid-loop). Uniform 3 gload_lds per
// K-step (1 A + 2 W) makes the vmcnt arithmetic static:
//   prologue: STAGE(0),STAGE(1) -> 6 outstanding; vmcnt(3) = buf0 ready.
//   iter kt: issue STAGE(kt+2) [3 ops]; compute buf[kt%3];
//            then vmcnt(3) (leaves kt+2's 3 in flight) = buf[kt+1] ready; s_barrier.
//   tail: vmcnt(0) before the last iteration.
// Raw s_barrier has no implicit waitcnt -- exactly the point (T4). ds_read->MFMA
// ordering is compiler-tracked (no inline-asm ds_read: rule #18 doesn't bite).
// In-place safe (out aliasing an identity A block): all global A reads drained
// by the vmcnt(0) before the final iteration; stores only in the epilogue.
// ---------------------------------------------------------------------------
__global__ __launch_bounds__(512, 4) void gemm_ssp_bf16_kernel(
    ASpec A, const unsigned short* __restrict__ W,
    void* __restrict__ out, int out_f32,
    const float* __restrict__ resid, int M)
{
    __shared__ unsigned short lds[3][12288];   // 3 x 24KB

    const int K    = A.nblocks * HID;
    const int lane = threadIdx.x & 63;
    const int wave = threadIdx.x >> 6;
    const int l15  = lane & 15;
    const int kg   = lane >> 4;
    const int wr   = wave >> 2;
    const int wc   = wave & 3;
    const int rowbase = blockIdx.x * 128;

    const int arow = rowbase + wave * 16 + l15;
    const int arc  = arow < M ? arow : (M - 1);
    auto mkap = [&](int b) -> const unsigned short* {
        if (b >= A.nblocks) return (const unsigned short*)A.base[0];
        const int rid = A.idx[b] ? A.idx[b][arc] : arc;
        return (const unsigned short*)A.base[b] + (size_t)rid * HID;
    };
    const unsigned short* ap0 = mkap(0);
    const unsigned short* ap1 = mkap(1);
    const unsigned short* ap2 = mkap(2);
    const unsigned short* ap3 = mkap(3);

    const unsigned short* wq0 = W + (size_t)((wave * 2 + 0) * 16 + l15) * K + kg * 8;
    const unsigned short* wq1 = W + (size_t)((wave * 2 + 1) * 16 + l15) * K + kg * 8;

    auto STAGE = [&](int buf, int kt) {
        unsigned short* ldsb = &lds[buf][0];
        const int b   = kt >> 3;
        const int kin = (kt & 7) * 32 + kg * 8;
        const unsigned short* ap = (b == 0) ? ap0 : (b == 1) ? ap1 : (b == 2) ? ap2 : ap3;
        gload_lds16(ap + kin, (char*)ldsb + wave * 1024);
        const int koff = kt * 32;
        gload_lds16(wq0 + koff, (char*)ldsb + 8192 + (wave * 2 + 0) * 1024);
        gload_lds16(wq1 + koff, (char*)ldsb + 8192 + (wave * 2 + 1) * 1024);
    };

    accf4 acc[4][4];
    #pragma unroll
    for (int m = 0; m < 4; m++)
        #pragma unroll
        for (int n = 0; n < 4; n++)
            acc[m][n] = (accf4){0.f, 0.f, 0.f, 0.f};

    const int ksteps = A.nblocks * 8;   // always >= 8

    STAGE(0, 0);
    STAGE(1, 1);
    asm volatile("s_waitcnt vmcnt(3)" ::: "memory");   // buf0 ready
    __builtin_amdgcn_s_barrier();

    int cur = 0;
    for (int kt = 0; kt < ksteps; ++kt) {
        const bool pf = (kt + 2) < ksteps;
        if (pf) {
            int nb = cur + 2; if (nb >= 3) nb -= 3;
            STAGE(nb, kt + 2);
        }
        const char* ldsb = (const char*)&lds[cur][0];
        const bfrag8 af0 = *(const bfrag8*)(ldsb + (wr * 4 + 0) * 1024 + lane * 16);
        const bfrag8 af1 = *(const bfrag8*)(ldsb + (wr * 4 + 1) * 1024 + lane * 16);
        const bfrag8 af2 = *(const bfrag8*)(ldsb + (wr * 4 + 2) * 1024 + lane * 16);
        const bfrag8 af3 = *(const bfrag8*)(ldsb + (wr * 4 + 3) * 1024 + lane * 16);
        #pragma unroll
        for (int n = 0; n < 4; n++) {
            const bfrag8 bfn = *(const bfrag8*)(ldsb + 8192 + (wc * 4 + n) * 1024 + lane * 16);
            acc[0][n] = __builtin_amdgcn_mfma_f32_16x16x32_bf16(af0, bfn, acc[0][n], 0, 0, 0);
            acc[1][n] = __builtin_amdgcn_mfma_f32_16x16x32_bf16(af1, bfn, acc[1][n], 0, 0, 0);
            acc[2][n] = __builtin_amdgcn_mfma_f32_16x16x32_bf16(af2, bfn, acc[2][n], 0, 0, 0);
            acc[3][n] = __builtin_amdgcn_mfma_f32_16x16x32_bf16(af3, bfn, acc[3][n], 0, 0, 0);
        }
        if (kt + 1 < ksteps) {
            if (pf) asm volatile("s_waitcnt vmcnt(3)" ::: "memory");  // buf[kt+1] ready
            else    asm volatile("s_waitcnt vmcnt(0)" ::: "memory");  // drain tail
            __builtin_amdgcn_s_barrier();
        }
        cur = cur + 1; if (cur >= 3) cur = 0;
    }

    #pragma unroll
    for (int m = 0; m < 4; m++) {
        #pragma unroll
        for (int rg = 0; rg < 4; rg++) {
            const int r = rowbase + wr * 64 + m * 16 + kg * 4 + rg;
            if (r < M) {
                #pragma unroll
                for (int n = 0; n < 4; n++) {
                    const int c = wc * 64 + n * 16 + l15;
                    const size_t off = (size_t)r * HID + c;
                    float v = sspf(acc[m][n][rg]);
                    if (resid) v += resid[off];
                    if (out_f32) ((float*)out)[off] = v;
                    else ((unsigned short*)out)[off] = f2bf(v);
                }
            }
        }
    }
}

__global__ void cvt_w_kernel(const float* __restrict__ src, unsigned short* __restrict__ dst, int n) {
    int i = blockIdx.x * 256 + threadIdx.x;
    if (i < n) dst[i] = f2bf(src[i]);
}

__global__ void be_counts_kernel(const int* __restrict__ src, const int* __restrict__ dst,
                                 const int* __restrict__ batch, int* __restrict__ be,
                                 int* __restrict__ cnt_dst, int* __restrict__ cnt_eg) {
    int e = blockIdx.x * 256 + threadIdx.x;
    if (e < NE) {
        int b = batch[src[e]];
        be[e] = b;
        atomicAdd(&cnt_dst[dst[e]], 1);
        atomicAdd(&cnt_eg[b], 1);
    }
}

__global__ void node_counts_kernel(const int* __restrict__ batch, int* __restrict__ cnt_ng) {
    int i = blockIdx.x * 256 + threadIdx.x;
    if (i < NN) atomicAdd(&cnt_ng[batch[i]], 1);
}

// single-block exclusive prefix scan: rowstart[0..n] from cnt[0..n-1]. 1024 threads.
__global__ void scan_kernel(const int* __restrict__ cnt, int* __restrict__ rowstart, int n) {
    __shared__ int part[1024];
    const int t = threadIdx.x;
    const int chunk = (n + 1023) / 1024;
    const int lo = t * chunk;
    const int hi = (lo + chunk < n) ? lo + chunk : n;
    int s = 0;
    for (int i = lo; i < hi; i++) s += cnt[i];
    part[t] = s;
    __syncthreads();
    for (int d = 1; d < 1024; d <<= 1) {
        int v = (t >= d) ? part[t - d] : 0;
        __syncthreads();
        part[t] += v;
        __syncthreads();
    }
    int base = (t > 0) ? part[t - 1] : 0;
    for (int i = lo; i < hi; i++) { rowstart[i] = base; base += cnt[i]; }
    if (t == 0) rowstart[n] = part[1023];
}

__global__ void fill_csr_kernel(const int* __restrict__ dst, const int* __restrict__ rowstart,
                                int* __restrict__ fill_cnt, int* __restrict__ eids) {
    int e = blockIdx.x * 256 + threadIdx.x;
    if (e < NE) {
        int d = dst[e];
        int pos = rowstart[d] + atomicAdd(&fill_cnt[d], 1);
        eids[pos] = e;
    }
}

// gather-mean of e_mid rows by dst-CSR: one block per node, 256 threads = cols.
// emid is f32 (ef32=1) or bf16 (ef32=0).
__global__ void e2n_mean_kernel(const void* __restrict__ emid, int ef32,
                                const int* __restrict__ rowstart,
                                const int* __restrict__ eids, unsigned short* __restrict__ out) {
    const int v = blockIdx.x;
    const int c = threadIdx.x;
    const int lo = rowstart[v], hi = rowstart[v + 1];
    float s = 0.f;
    if (ef32) {
        const float* p = (const float*)emid;
        for (int j = lo; j < hi; j++) s += p[(size_t)eids[j] * HID + c];
    } else {
        const unsigned short* p = (const unsigned short*)emid;
        for (int j = lo; j < hi; j++) s += bf2f(p[(size_t)eids[j] * HID + c]);
    }
    const float m = (hi > lo) ? s / (float)(hi - lo) : 0.f;
    out[(size_t)v * HID + c] = f2bf(m);
}

// LDS-binned e2g sum: grid = E2G_CHUNKS x 4 colgroups, block 256 (4 edges x 64 cols).
__global__ void e2g_bin_kernel(const void* __restrict__ emid, int ef32,
                               const int* __restrict__ be, float* __restrict__ e2g_sum) {
    __shared__ float bins[NG][64];   // 32 KB
    const int cg    = blockIdx.x & 3;
    const int chunk = blockIdx.x >> 2;
    for (int i = threadIdx.x; i < NG * 64; i += 256) ((float*)bins)[i] = 0.f;
    __syncthreads();
    const int per = (NE + E2G_CHUNKS - 1) / E2G_CHUNKS;
    const int lo = chunk * per;
    const int hi = (lo + per < NE) ? lo + per : NE;
    const int esub = threadIdx.x >> 6;
    const int c    = threadIdx.x & 63;
    for (int e0 = lo; e0 < hi; e0 += 4) {
        const int e = e0 + esub;
        if (e < hi) {
            const size_t idx = (size_t)e * HID + cg * 64 + c;
            float v = ef32 ? ((const float*)emid)[idx]
                           : bf2f(((const unsigned short*)emid)[idx]);
            atomicAdd(&bins[be[e]][c], v);
        }
    }
    __syncthreads();
    for (int i = threadIdx.x; i < NG * 64; i += 256) {
        const int g = i >> 6, cc = i & 63;
        const float v = ((float*)bins)[i];
        if (v != 0.f) atomicAdd(&e2g_sum[(size_t)g * HID + cg * 64 + cc], v);
    }
}

// n2g mean: batch is sorted -> contiguous node segments per graph. Block per graph.
__global__ void n2g_mean_kernel(const unsigned short* __restrict__ nmid,
                                const int* __restrict__ noderow,
                                unsigned short* __restrict__ out) {
    const int g = blockIdx.x;
    const int c = threadIdx.x;
    const int lo = noderow[g], hi = noderow[g + 1];
    float s = 0.f;
    for (int i = lo; i < hi; i++)
        s += bf2f(nmid[(size_t)i * HID + c]);
    out[(size_t)g * HID + c] = f2bf((hi > lo) ? s / (float)(hi - lo) : 0.f);
}

__global__ void e2g_mean_kernel(const float* __restrict__ sum, const int* __restrict__ cnt,
                                unsigned short* __restrict__ out) {
    int gid = blockIdx.x * 256 + threadIdx.x;
    if (gid < NG * HID)
        out[gid] = f2bf(sum[gid] / fmaxf((float)cnt[gid >> 8], 1.f));
}

extern "C" void kernel_launch(void* const* d_in, const int* in_sizes, int n_in,
                              void* d_out, int out_size, void* d_ws, size_t ws_size,
                              hipStream_t stream)
{
    (void)in_sizes; (void)n_in; (void)out_size;
    const float* node_feats = (const float*)d_in[0];
    const float* edge_feats = (const float*)d_in[1];
    const float* glob_feats = (const float*)d_in[2];
    const int* edge_index   = (const int*)d_in[3];
    const int* batch        = (const int*)d_in[4];
    const float* Wf[9] = {
        (const float*)d_in[5],  (const float*)d_in[6],  (const float*)d_in[7],
        (const float*)d_in[8],  (const float*)d_in[9],  (const float*)d_in[10],
        (const float*)d_in[11], (const float*)d_in[12], (const float*)d_in[13],
    };
    const int Wn[9] = { HID*HID, HID*HID, HID*HID,
                        HID*4*HID, HID*3*HID, HID*3*HID,
                        HID*HID, HID*HID, HID*HID };

    const int* src = edge_index;        // edge_index[0]
    const int* dst = edge_index + NE;   // edge_index[1]

    float* out_n = (float*)d_out;                       // [NN,256] f32
    float* out_e = out_n + (size_t)NN * HID;            // [NE,256] f32
    float* out_g = out_e + (size_t)NE * HID;            // [NG,256] f32

    // ws layout. Zero-init region first -> single memsetAsync (~0.3 MB).
    char* ws = (char*)d_ws;
    size_t off = 0;
    auto alloc = [&](size_t bytes) -> char* {
        char* p = ws + off; off += (bytes + 255) & ~(size_t)255; return p;
    };
    float* e2g_sum = (float*)alloc((size_t)NG * HID * 4);
    int* cnt_dst   = (int*)alloc((size_t)NN * 4);
    int* fill_cnt  = (int*)alloc((size_t)NN * 4);
    int* cnt_eg    = (int*)alloc((size_t)NG * 4);
    int* cnt_ng    = (int*)alloc((size_t)NG * 4);
    size_t zero_bytes = off;
    hipMemsetAsync(d_ws, 0, zero_bytes, stream);

    int* rowstart_dst        = (int*)alloc((size_t)(NN + 1) * 4);
    int* noderow             = (int*)alloc((size_t)(NG + 1) * 4);
    int* eids                = (int*)alloc((size_t)NE * 4);
    int* be                  = (int*)alloc((size_t)NE * 4);
    unsigned short* n1       = (unsigned short*)alloc((size_t)NN * HID * 2);
    unsigned short* g1       = (unsigned short*)alloc((size_t)NG * HID * 2);
    unsigned short* e2n_mean = (unsigned short*)alloc((size_t)NN * HID * 2);
    unsigned short* n_mid    = (unsigned short*)alloc((size_t)NN * HID * 2);
    unsigned short* n2g_mean = (unsigned short*)alloc((size_t)NG * HID * 2);
    unsigned short* e2g_mean = (unsigned short*)alloc((size_t)NG * HID * 2);
    unsigned short* g_mid    = (unsigned short*)alloc((size_t)NG * HID * 2);
    unsigned short* Wb[9];
    for (int i = 0; i < 9; i++) Wb[i] = (unsigned short*)alloc((size_t)Wn[i] * 2);

    // Fast path: bf16 e-stream (e1/e_mid share one 102 MB buffer, edge-MLP runs
    // in place on it) -> uniform all-bf16 A for the big GEMMs (pipelined kernel)
    // + ~400 MB less HBM traffic. Gated on ws_size; fallback = r5 behavior.
    const size_t ebuf_bytes = (size_t)NE * HID * 2;
    const bool fast = (off + ebuf_bytes) <= ws_size;
    unsigned short* ebuf = fast ? (unsigned short*)alloc(ebuf_bytes) : nullptr;

    // Fallback aliases into d_out:
    float* e1_f32    = out_e;   // stage-1 edge activations, f32, in place
    float* e_mid_f32 = out_e;   // edge-MLP output, f32, in place (identity rows)

    // weights -> bf16 (9 tiny launches, 1M elements total)
    for (int i = 0; i < 9; i++)
        cvt_w_kernel<<<(Wn[i] + 255) / 256, 256, 0, stream>>>(Wf[i], Wb[i], Wn[i]);

    // graph/CSR setup (all tiny)
    be_counts_kernel<<<(NE + 255) / 256, 256, 0, stream>>>(src, dst, batch, be, cnt_dst, cnt_eg);
    node_counts_kernel<<<(NN + 255) / 256, 256, 0, stream>>>(batch, cnt_ng);
    scan_kernel<<<1, 1024, 0, stream>>>(cnt_dst, rowstart_dst, NN);
    scan_kernel<<<1, 1024, 0, stream>>>(cnt_ng, noderow, NG);
    fill_csr_kernel<<<(NE + 255) / 256, 256, 0, stream>>>(dst, rowstart_dst, fill_cnt, eids);

    auto launch_gemm = [&](const ASpec& A, const unsigned short* W,
                           void* o, int of32, const float* resid, int M) {
        gemm_ssp_kernel<<<(M + 127) / 128, 512, 0, stream>>>(A, W, o, of32, resid, M);
    };
    auto launch_gemm_bf16 = [&](const ASpec& A, const unsigned short* W,
                                void* o, int of32, const float* resid, int M) {
        gemm_ssp_bf16_kernel<<<(M + 127) / 128, 512, 0, stream>>>(A, W, o, of32, resid, M);
    };

    // stage 1: lin_*_1 + ssp (f32 inputs -> generic kernel)
    { ASpec a{}; a.base[0] = node_feats; a.f32mask = 1; a.nblocks = 1;
      launch_gemm(a, Wb[0], n1, 0, nullptr, NN); }
    { ASpec a{}; a.base[0] = edge_feats; a.f32mask = 1; a.nblocks = 1;
      if (fast) launch_gemm(a, Wb[1], ebuf, 0, nullptr, NE);      // e1 bf16
      else      launch_gemm(a, Wb[1], e1_f32, 1, nullptr, NE); }  // e1 f32 in d_out
    { ASpec a{}; a.base[0] = glob_feats; a.f32mask = 1; a.nblocks = 1;
      launch_gemm(a, Wb[2], g1, 0, nullptr, NG); }

    // EdgeModel: gather-concat fused into A-load, K=1024
    const void* emid_src; int emid_f32;
    if (fast) {
        ASpec a{};
        a.base[0] = n1;   a.idx[0] = src;
        a.base[1] = n1;   a.idx[1] = dst;
        a.base[2] = ebuf; a.idx[2] = nullptr;
        a.base[3] = g1;   a.idx[3] = be;
        a.f32mask = 0; a.nblocks = 4;
        launch_gemm_bf16(a, Wb[3], ebuf, 0, nullptr, NE);   // in place, bf16 out
        emid_src = ebuf; emid_f32 = 0;
    } else {
        ASpec a{};
        a.base[0] = n1;     a.idx[0] = src;
        a.base[1] = n1;     a.idx[1] = dst;
        a.base[2] = e1_f32; a.idx[2] = nullptr;
        a.base[3] = g1;     a.idx[3] = be;
        a.f32mask = 0b0100; a.nblocks = 4;
        launch_gemm(a, Wb[3], e_mid_f32, 1, nullptr, NE);
        emid_src = e_mid_f32; emid_f32 = 1;
    }

    // scatter-means via gather / LDS bins (no bulk global atomics)
    e2n_mean_kernel<<<NN, 256, 0, stream>>>(emid_src, emid_f32, rowstart_dst, eids, e2n_mean);
    e2g_bin_kernel<<<E2G_CHUNKS * 4, 256, 0, stream>>>(emid_src, emid_f32, be, e2g_sum);
    e2g_mean_kernel<<<(NG * HID + 255) / 256, 256, 0, stream>>>(e2g_sum, cnt_eg, e2g_mean);

    // NodeModel: K=768 -> n_mid bf16 (all-bf16 A -> pipelined kernel)
    { ASpec a{};
      a.base[0] = n1;
      a.base[1] = e2n_mean;
      a.base[2] = g1; a.idx[2] = batch;
      a.f32mask = 0; a.nblocks = 3;
      launch_gemm_bf16(a, Wb[4], n_mid, 0, nullptr, NN); }

    // nodes -> graphs mean (batch sorted -> contiguous segments, no atomics)
    n2g_mean_kernel<<<NG, 256, 0, stream>>>(n_mid, noderow, n2g_mean);

    // GlobalModel: K=768 -> g_mid bf16
    { ASpec a{};
      a.base[0] = n2g_mean; a.base[1] = e2g_mean; a.base[2] = g1;
      a.f32mask = 0; a.nblocks = 3;
      launch_gemm_bf16(a, Wb[5], g_mid, 0, nullptr, NG); }

    // final lin_*_2 + ssp + residual -> f32 d_out
    { ASpec a{}; a.base[0] = n_mid; a.f32mask = 0; a.nblocks = 1;
      launch_gemm_bf16(a, Wb[6], out_n, 1, node_feats, NN); }
    if (fast) {
        ASpec a{}; a.base[0] = ebuf; a.f32mask = 0; a.nblocks = 1;
        launch_gemm_bf16(a, Wb[7], out_e, 1, edge_feats, NE);
    } else {
        ASpec a{}; a.base[0] = e_mid_f32; a.f32mask = 1; a.nblocks = 1;
        launch_gemm(a, Wb[7], out_e, 1, edge_feats, NE);   // in place on out_e
    }
    { ASpec a{}; a.base[0] = g_mid; a.f32mask = 0; a.nblocks = 1;
      launch_gemm_bf16(a, Wb[8], out_g, 1, glob_feats, NG); }
}

// Round 7
// 1865.206 us; speedup vs baseline: 1.7600x; 1.0237x over previous
//
#include <hip/hip_runtime.h>
#include <hip/hip_bf16.h>
#include <cstdint>
#include <cstddef>

#define NN 20000
#define NE 200000
#define NG 128
#define HID 256
#define E2G_CHUNKS 64   // edge chunks for the LDS-binned e2g reduction

typedef __bf16 bfrag8 __attribute__((ext_vector_type(8)));  // 8 bf16 (4 VGPRs)
typedef float  accf4  __attribute__((ext_vector_type(4)));  // 4 fp32 acc

__device__ __forceinline__ unsigned short f2bf(float f) {
    union { float f; unsigned int i; } x; x.f = f;
    unsigned int r = x.i + 0x7fffu + ((x.i >> 16) & 1u);  // RNE
    return (unsigned short)(r >> 16);
}
__device__ __forceinline__ __bf16 f2bf16t(float f) {
    union { unsigned short u; __bf16 b; } x; x.u = f2bf(f); return x.b;
}
__device__ __forceinline__ float bf2f(unsigned short u) {
    union { unsigned int i; float f; } x; x.i = ((unsigned int)u) << 16; return x.f;
}
// softplus(x) - log(2) via HW transcendentals (v_exp_f32/v_log_f32, ~7 insts).
// r5 lesson: libm log1pf/expf cost ~40+ VALU insts -> epilogue VALU-bound.
__device__ __forceinline__ float sspf(float x) {
    float e = __expf(-fabsf(x));
    return fmaxf(x, 0.f) + __logf(1.f + e) - 0.69314718055994530942f;
}

// async 16B global -> LDS (per-lane global addr, lane-linear LDS dest: base + lane*16)
__device__ __forceinline__ void gload_lds16(const void* g, void* l) {
    __builtin_amdgcn_global_load_lds(
        (const __attribute__((address_space(1))) unsigned int*)g,
        (__attribute__((address_space(3))) unsigned int*)l,
        16, 0, 0);
}

// A-operand spec: virtual A[M, nblocks*256] = concat of up to 4 [.,256] sources,
// each with optional row-index indirection (nullptr => identity) and a per-block
// dtype flag (f32mask bit b set => base[b] is const float*, else bf16).
struct ASpec {
    const void* base[4];
    const int* idx[4];
    int f32mask;
    int nblocks;
};

// ---------------------------------------------------------------------------
// Generic GEMM (supports f32 A-blocks): 2-barrier double-buffered structure.
// tile = 128x256, 8 waves, K-step 32, LDS 2x24KB. Used for stage-1 (f32 inputs)
// and the fallback path.
// Reg budget (r4 lesson): (512,4) -> cap 128; acc in AGPR (64) + ~60 VGPR, no spill.
// r2 lesson: no global atomics in epilogues.
// ---------------------------------------------------------------------------
__global__ __launch_bounds__(512, 4) void gemm_ssp_kernel(
    ASpec A, const unsigned short* __restrict__ W,
    void* __restrict__ out, int out_f32,
    const float* __restrict__ resid, int M)
{
    __shared__ unsigned short lds[2][12288];   // 2 x 24KB: [A: 8*512 | W: 16*512] shorts

    const int K    = A.nblocks * HID;
    const int lane = threadIdx.x & 63;
    const int wave = threadIdx.x >> 6;
    const int l15  = lane & 15;
    const int kg   = lane >> 4;
    const int wr   = wave >> 2;      // row-group 0..1
    const int wc   = wave & 3;       // col-group 0..3
    const int rowbase = blockIdx.x * 128;

    const int arow = rowbase + wave * 16 + l15;
    const int arc  = arow < M ? arow : (M - 1);
    auto mkap = [&](int b) -> const char* {
        if (b >= A.nblocks) return (const char*)A.base[0];
        const int rid = A.idx[b] ? A.idx[b][arc] : arc;
        const int e4 = (A.f32mask >> b) & 1;
        return (const char*)A.base[b] + (size_t)rid * (size_t)(HID * (e4 ? 4 : 2));
    };
    const char* ap0 = mkap(0);
    const char* ap1 = mkap(1);
    const char* ap2 = mkap(2);
    const char* ap3 = mkap(3);

    const unsigned short* wq0 = W + (size_t)((wave * 2 + 0) * 16 + l15) * K + kg * 8;
    const unsigned short* wq1 = W + (size_t)((wave * 2 + 1) * 16 + l15) * K + kg * 8;

    auto STAGE = [&](int buf, int kt) {
        unsigned short* ldsb = &lds[buf][0];
        const int b   = kt >> 3;
        const int kin = (kt & 7) * 32 + kg * 8;
        const char* ap = (b == 0) ? ap0 : (b == 1) ? ap1 : (b == 2) ? ap2 : ap3;
        if ((A.f32mask >> b) & 1) {
            const float* p = (const float*)ap + kin;
            const float4 x = ((const float4*)p)[0];
            const float4 y = ((const float4*)p)[1];
            bfrag8 f;
            f[0] = f2bf16t(x.x); f[1] = f2bf16t(x.y);
            f[2] = f2bf16t(x.z); f[3] = f2bf16t(x.w);
            f[4] = f2bf16t(y.x); f[5] = f2bf16t(y.y);
            f[6] = f2bf16t(y.z); f[7] = f2bf16t(y.w);
            *(bfrag8*)((char*)ldsb + wave * 1024 + lane * 16) = f;
        } else {
            gload_lds16((const unsigned short*)ap + kin, (char*)ldsb + wave * 1024);
        }
        const int koff = kt * 32;
        gload_lds16(wq0 + koff, (char*)ldsb + 8192 + (wave * 2 + 0) * 1024);
        gload_lds16(wq1 + koff, (char*)ldsb + 8192 + (wave * 2 + 1) * 1024);
    };

    accf4 acc[4][4];
    #pragma unroll
    for (int m = 0; m < 4; m++)
        #pragma unroll
        for (int n = 0; n < 4; n++)
            acc[m][n] = (accf4){0.f, 0.f, 0.f, 0.f};

    const int ksteps = A.nblocks * 8;

    STAGE(0, 0);
    __syncthreads();

    for (int kt = 0; kt < ksteps; ++kt) {
        const int cur = kt & 1;
        if (kt + 1 < ksteps) STAGE(cur ^ 1, kt + 1);

        const char* ldsb = (const char*)&lds[cur][0];
        const bfrag8 af0 = *(const bfrag8*)(ldsb + (wr * 4 + 0) * 1024 + lane * 16);
        const bfrag8 af1 = *(const bfrag8*)(ldsb + (wr * 4 + 1) * 1024 + lane * 16);
        const bfrag8 af2 = *(const bfrag8*)(ldsb + (wr * 4 + 2) * 1024 + lane * 16);
        const bfrag8 af3 = *(const bfrag8*)(ldsb + (wr * 4 + 3) * 1024 + lane * 16);
        #pragma unroll
        for (int n = 0; n < 4; n++) {
            const bfrag8 bfn = *(const bfrag8*)(ldsb + 8192 + (wc * 4 + n) * 1024 + lane * 16);
            acc[0][n] = __builtin_amdgcn_mfma_f32_16x16x32_bf16(af0, bfn, acc[0][n], 0, 0, 0);
            acc[1][n] = __builtin_amdgcn_mfma_f32_16x16x32_bf16(af1, bfn, acc[1][n], 0, 0, 0);
            acc[2][n] = __builtin_amdgcn_mfma_f32_16x16x32_bf16(af2, bfn, acc[2][n], 0, 0, 0);
            acc[3][n] = __builtin_amdgcn_mfma_f32_16x16x32_bf16(af3, bfn, acc[3][n], 0, 0, 0);
        }

        __syncthreads();
    }

    #pragma unroll
    for (int m = 0; m < 4; m++) {
        #pragma unroll
        for (int rg = 0; rg < 4; rg++) {
            const int r = rowbase + wr * 64 + m * 16 + kg * 4 + rg;
            if (r < M) {
                #pragma unroll
                for (int n = 0; n < 4; n++) {
                    const int c = wc * 64 + n * 16 + l15;
                    const size_t off = (size_t)r * HID + c;
                    float v = sspf(acc[m][n][rg]);
                    if (resid) v += resid[off];
                    if (out_f32) ((float*)out)[off] = v;
                    else ((unsigned short*)out)[off] = f2bf(v);
                }
            }
        }
    }
}

// ---------------------------------------------------------------------------
// Two-pass fused GEMM (all-bf16 A), pipelined (T3/T4):
//   pass1: mid[M,256] = ssp( A[M,K1] @ W1[256,K1]^T )   (bf16 store)
//   drain stores (vmcnt 0) + s_barrier                 (own 128 rows now L2-hot)
//   pass2: out2[M,256] = ssp( mid[M,256] @ W2[256,256]^T ) + resid  (f32 store)
// Both passes use the counted-vmcnt schedule: triple-buffered LDS (3x24KB),
// depth-2 prefetch, uniform 3 gload_lds per K-step (1 A + 2 W):
//   prologue: STAGE(0),STAGE(1) -> 6 outstanding; vmcnt(3) = buf0 ready.
//   iter kt: STAGE(kt+2); compute buf[kt%3]; vmcnt(3) (or 0 at tail); s_barrier.
// Raw s_barrier has no implicit waitcnt -- prefetch loads stay in flight across
// barriers (never drain mid-loop). The fusion removes the separate out_* GEMM
// launches (r6 theory: out_e alone ~510MB at latency-bound rates ~400us) and
// converts mid's HBM re-read into same-CU L2 hits.
// In-place safe (mid aliasing an identity A block): all pass-1 A reads drained
// by vmcnt(0) before the last iteration; pass-2 reads only the block's own rows,
// written+drained before the inter-pass barrier.
// ---------------------------------------------------------------------------
__global__ __launch_bounds__(512, 4) void gemm_ssp_fused2_kernel(
    ASpec A, const unsigned short* __restrict__ W1,
    unsigned short* __restrict__ mid,
    const unsigned short* __restrict__ W2,
    const float* __restrict__ resid, float* __restrict__ out2, int M)
{
    __shared__ unsigned short lds[3][12288];   // 3 x 24KB

    const int K1   = A.nblocks * HID;
    const int lane = threadIdx.x & 63;
    const int wave = threadIdx.x >> 6;
    const int l15  = lane & 15;
    const int kg   = lane >> 4;
    const int wr   = wave >> 2;
    const int wc   = wave & 3;
    const int rowbase = blockIdx.x * 128;

    const int arow = rowbase + wave * 16 + l15;
    const int arc  = arow < M ? arow : (M - 1);
    auto mkap = [&](int b) -> const unsigned short* {
        if (b >= A.nblocks) return (const unsigned short*)A.base[0];
        const int rid = A.idx[b] ? A.idx[b][arc] : arc;
        return (const unsigned short*)A.base[b] + (size_t)rid * HID;
    };
    const unsigned short* ap0 = mkap(0);
    const unsigned short* ap1 = mkap(1);
    const unsigned short* ap2 = mkap(2);
    const unsigned short* ap3 = mkap(3);

    const unsigned short* wq0 = W1 + (size_t)((wave * 2 + 0) * 16 + l15) * K1 + kg * 8;
    const unsigned short* wq1 = W1 + (size_t)((wave * 2 + 1) * 16 + l15) * K1 + kg * 8;

    auto STAGE = [&](int buf, int kt) {
        unsigned short* ldsb = &lds[buf][0];
        const int b   = kt >> 3;
        const int kin = (kt & 7) * 32 + kg * 8;
        const unsigned short* ap = (b == 0) ? ap0 : (b == 1) ? ap1 : (b == 2) ? ap2 : ap3;
        gload_lds16(ap + kin, (char*)ldsb + wave * 1024);
        const int koff = kt * 32;
        gload_lds16(wq0 + koff, (char*)ldsb + 8192 + (wave * 2 + 0) * 1024);
        gload_lds16(wq1 + koff, (char*)ldsb + 8192 + (wave * 2 + 1) * 1024);
    };

    accf4 acc[4][4];
    #pragma unroll
    for (int m = 0; m < 4; m++)
        #pragma unroll
        for (int n = 0; n < 4; n++)
            acc[m][n] = (accf4){0.f, 0.f, 0.f, 0.f};

    const int ksteps = A.nblocks * 8;   // >= 8

    STAGE(0, 0);
    STAGE(1, 1);
    asm volatile("s_waitcnt vmcnt(3)" ::: "memory");
    __builtin_amdgcn_s_barrier();

    int cur = 0;
    for (int kt = 0; kt < ksteps; ++kt) {
        const bool pf = (kt + 2) < ksteps;
        if (pf) {
            int nb = cur + 2; if (nb >= 3) nb -= 3;
            STAGE(nb, kt + 2);
        }
        const char* ldsb = (const char*)&lds[cur][0];
        const bfrag8 af0 = *(const bfrag8*)(ldsb + (wr * 4 + 0) * 1024 + lane * 16);
        const bfrag8 af1 = *(const bfrag8*)(ldsb + (wr * 4 + 1) * 1024 + lane * 16);
        const bfrag8 af2 = *(const bfrag8*)(ldsb + (wr * 4 + 2) * 1024 + lane * 16);
        const bfrag8 af3 = *(const bfrag8*)(ldsb + (wr * 4 + 3) * 1024 + lane * 16);
        #pragma unroll
        for (int n = 0; n < 4; n++) {
            const bfrag8 bfn = *(const bfrag8*)(ldsb + 8192 + (wc * 4 + n) * 1024 + lane * 16);
            acc[0][n] = __builtin_amdgcn_mfma_f32_16x16x32_bf16(af0, bfn, acc[0][n], 0, 0, 0);
            acc[1][n] = __builtin_amdgcn_mfma_f32_16x16x32_bf16(af1, bfn, acc[1][n], 0, 0, 0);
            acc[2][n] = __builtin_amdgcn_mfma_f32_16x16x32_bf16(af2, bfn, acc[2][n], 0, 0, 0);
            acc[3][n] = __builtin_amdgcn_mfma_f32_16x16x32_bf16(af3, bfn, acc[3][n], 0, 0, 0);
        }
        if (kt + 1 < ksteps) {
            if (pf) asm volatile("s_waitcnt vmcnt(3)" ::: "memory");
            else    asm volatile("s_waitcnt vmcnt(0)" ::: "memory");
            __builtin_amdgcn_s_barrier();
        }
        cur = cur + 1; if (cur >= 3) cur = 0;
    }

    // epilogue 1: mid = ssp(acc), bf16
    #pragma unroll
    for (int m = 0; m < 4; m++) {
        #pragma unroll
        for (int rg = 0; rg < 4; rg++) {
            const int r = rowbase + wr * 64 + m * 16 + kg * 4 + rg;
            if (r < M) {
                #pragma unroll
                for (int n = 0; n < 4; n++) {
                    const int c = wc * 64 + n * 16 + l15;
                    mid[(size_t)r * HID + c] = f2bf(sspf(acc[m][n][rg]));
                }
            }
        }
    }

    // inter-pass: drain stores (vmcnt tracks stores on gfx9), then block-sync.
    asm volatile("s_waitcnt vmcnt(0)" ::: "memory");
    __builtin_amdgcn_s_barrier();

    // ---- pass 2: out2 = ssp(mid @ W2^T) + resid, K=256 (8 ksteps) ----
    #pragma unroll
    for (int m = 0; m < 4; m++)
        #pragma unroll
        for (int n = 0; n < 4; n++)
            acc[m][n] = (accf4){0.f, 0.f, 0.f, 0.f};

    const unsigned short* mp   = mid + (size_t)arc * HID;                       // own row
    const unsigned short* w2q0 = W2 + (size_t)((wave * 2 + 0) * 16 + l15) * HID + kg * 8;
    const unsigned short* w2q1 = W2 + (size_t)((wave * 2 + 1) * 16 + l15) * HID + kg * 8;

    auto STAGE2 = [&](int buf, int kt) {
        unsigned short* ldsb = &lds[buf][0];
        const int koff = kt * 32;
        gload_lds16(mp + koff + kg * 8, (char*)ldsb + wave * 1024);
        gload_lds16(w2q0 + koff, (char*)ldsb + 8192 + (wave * 2 + 0) * 1024);
        gload_lds16(w2q1 + koff, (char*)ldsb + 8192 + (wave * 2 + 1) * 1024);
    };

    STAGE2(0, 0);
    STAGE2(1, 1);
    asm volatile("s_waitcnt vmcnt(3)" ::: "memory");
    __builtin_amdgcn_s_barrier();

    cur = 0;
    for (int kt = 0; kt < 8; ++kt) {
        const bool pf = (kt + 2) < 8;
        if (pf) {
            int nb = cur + 2; if (nb >= 3) nb -= 3;
            STAGE2(nb, kt + 2);
        }
        const char* ldsb = (const char*)&lds[cur][0];
        const bfrag8 af0 = *(const bfrag8*)(ldsb + (wr * 4 + 0) * 1024 + lane * 16);
        const bfrag8 af1 = *(const bfrag8*)(ldsb + (wr * 4 + 1) * 1024 + lane * 16);
        const bfrag8 af2 = *(const bfrag8*)(ldsb + (wr * 4 + 2) * 1024 + lane * 16);
        const bfrag8 af3 = *(const bfrag8*)(ldsb + (wr * 4 + 3) * 1024 + lane * 16);
        #pragma unroll
        for (int n = 0; n < 4; n++) {
            const bfrag8 bfn = *(const bfrag8*)(ldsb + 8192 + (wc * 4 + n) * 1024 + lane * 16);
            acc[0][n] = __builtin_amdgcn_mfma_f32_16x16x32_bf16(af0, bfn, acc[0][n], 0, 0, 0);
            acc[1][n] = __builtin_amdgcn_mfma_f32_16x16x32_bf16(af1, bfn, acc[1][n], 0, 0, 0);
            acc[2][n] = __builtin_amdgcn_mfma_f32_16x16x32_bf16(af2, bfn, acc[2][n], 0, 0, 0);
            acc[3][n] = __builtin_amdgcn_mfma_f32_16x16x32_bf16(af3, bfn, acc[3][n], 0, 0, 0);
        }
        if (kt + 1 < 8) {
            if (pf) asm volatile("s_waitcnt vmcnt(3)" ::: "memory");
            else    asm volatile("s_waitcnt vmcnt(0)" ::: "memory");
            __builtin_amdgcn_s_barrier();
        }
        cur = cur + 1; if (cur >= 3) cur = 0;
    }

    // epilogue 2: out2 = ssp(acc) + resid, f32
    #pragma unroll
    for (int m = 0; m < 4; m++) {
        #pragma unroll
        for (int rg = 0; rg < 4; rg++) {
            const int r = rowbase + wr * 64 + m * 16 + kg * 4 + rg;
            if (r < M) {
                #pragma unroll
                for (int n = 0; n < 4; n++) {
                    const int c = wc * 64 + n * 16 + l15;
                    const size_t off = (size_t)r * HID + c;
                    float v = sspf(acc[m][n][rg]);
                    if (resid) v += resid[off];
                    out2[off] = v;
                }
            }
        }
    }
}

__global__ void cvt_w_kernel(const float* __restrict__ src, unsigned short* __restrict__ dst, int n) {
    int i = blockIdx.x * 256 + threadIdx.x;
    if (i < n) dst[i] = f2bf(src[i]);
}

__global__ void be_counts_kernel(const int* __restrict__ src, const int* __restrict__ dst,
                                 const int* __restrict__ batch, int* __restrict__ be,
                                 int* __restrict__ cnt_dst, int* __restrict__ cnt_eg) {
    int e = blockIdx.x * 256 + threadIdx.x;
    if (e < NE) {
        int b = batch[src[e]];
        be[e] = b;
        atomicAdd(&cnt_dst[dst[e]], 1);
        atomicAdd(&cnt_eg[b], 1);
    }
}

__global__ void node_counts_kernel(const int* __restrict__ batch, int* __restrict__ cnt_ng) {
    int i = blockIdx.x * 256 + threadIdx.x;
    if (i < NN) atomicAdd(&cnt_ng[batch[i]], 1);
}

// single-block exclusive prefix scan: rowstart[0..n] from cnt[0..n-1]. 1024 threads.
__global__ void scan_kernel(const int* __restrict__ cnt, int* __restrict__ rowstart, int n) {
    __shared__ int part[1024];
    const int t = threadIdx.x;
    const int chunk = (n + 1023) / 1024;
    const int lo = t * chunk;
    const int hi = (lo + chunk < n) ? lo + chunk : n;
    int s = 0;
    for (int i = lo; i < hi; i++) s += cnt[i];
    part[t] = s;
    __syncthreads();
    for (int d = 1; d < 1024; d <<= 1) {
        int v = (t >= d) ? part[t - d] : 0;
        __syncthreads();
        part[t] += v;
        __syncthreads();
    }
    int base = (t > 0) ? part[t - 1] : 0;
    for (int i = lo; i < hi; i++) { rowstart[i] = base; base += cnt[i]; }
    if (t == 0) rowstart[n] = part[1023];
}

__global__ void fill_csr_kernel(const int* __restrict__ dst, const int* __restrict__ rowstart,
                                int* __restrict__ fill_cnt, int* __restrict__ eids) {
    int e = blockIdx.x * 256 + threadIdx.x;
    if (e < NE) {
        int d = dst[e];
        int pos = rowstart[d] + atomicAdd(&fill_cnt[d], 1);
        eids[pos] = e;
    }
}

// gather-mean of e_mid rows by dst-CSR: one block per node, 256 threads = cols.
// emid is f32 (ef32=1) or bf16 (ef32=0).
__global__ void e2n_mean_kernel(const void* __restrict__ emid, int ef32,
                                const int* __restrict__ rowstart,
                                const int* __restrict__ eids, unsigned short* __restrict__ out) {
    const int v = blockIdx.x;
    const int c = threadIdx.x;
    const int lo = rowstart[v], hi = rowstart[v + 1];
    float s = 0.f;
    if (ef32) {
        const float* p = (const float*)emid;
        for (int j = lo; j < hi; j++) s += p[(size_t)eids[j] * HID + c];
    } else {
        const unsigned short* p = (const unsigned short*)emid;
        for (int j = lo; j < hi; j++) s += bf2f(p[(size_t)eids[j] * HID + c]);
    }
    const float m = (hi > lo) ? s / (float)(hi - lo) : 0.f;
    out[(size_t)v * HID + c] = f2bf(m);
}

// LDS-binned e2g sum: grid = E2G_CHUNKS x 4 colgroups, block 256 (4 edges x 64 cols).
__global__ void e2g_bin_kernel(const void* __restrict__ emid, int ef32,
                               const int* __restrict__ be, float* __restrict__ e2g_sum) {
    __shared__ float bins[NG][64];   // 32 KB
    const int cg    = blockIdx.x & 3;
    const int chunk = blockIdx.x >> 2;
    for (int i = threadIdx.x; i < NG * 64; i += 256) ((float*)bins)[i] = 0.f;
    __syncthreads();
    const int per = (NE + E2G_CHUNKS - 1) / E2G_CHUNKS;
    const int lo = chunk * per;
    const int hi = (lo + per < NE) ? lo + per : NE;
    const int esub = threadIdx.x >> 6;
    const int c    = threadIdx.x & 63;
    for (int e0 = lo; e0 < hi; e0 += 4) {
        const int e = e0 + esub;
        if (e < hi) {
            const size_t idx = (size_t)e * HID + cg * 64 + c;
            float v = ef32 ? ((const float*)emid)[idx]
                           : bf2f(((const unsigned short*)emid)[idx]);
            atomicAdd(&bins[be[e]][c], v);
        }
    }
    __syncthreads();
    for (int i = threadIdx.x; i < NG * 64; i += 256) {
        const int g = i >> 6, cc = i & 63;
        const float v = ((float*)bins)[i];
        if (v != 0.f) atomicAdd(&e2g_sum[(size_t)g * HID + cg * 64 + cc], v);
    }
}

// n2g mean: batch is sorted -> contiguous node segments per graph. Block per graph.
__global__ void n2g_mean_kernel(const unsigned short* __restrict__ nmid,
                                const int* __restrict__ noderow,
                                unsigned short* __restrict__ out) {
    const int g = blockIdx.x;
    const int c = threadIdx.x;
    const int lo = noderow[g], hi = noderow[g + 1];
    float s = 0.f;
    for (int i = lo; i < hi; i++)
        s += bf2f(nmid[(size_t)i * HID + c]);
    out[(size_t)g * HID + c] = f2bf((hi > lo) ? s / (float)(hi - lo) : 0.f);
}

__global__ void e2g_mean_kernel(const float* __restrict__ sum, const int* __restrict__ cnt,
                                unsigned short* __restrict__ out) {
    int gid = blockIdx.x * 256 + threadIdx.x;
    if (gid < NG * HID)
        out[gid] = f2bf(sum[gid] / fmaxf((float)cnt[gid >> 8], 1.f));
}

extern "C" void kernel_launch(void* const* d_in, const int* in_sizes, int n_in,
                              void* d_out, int out_size, void* d_ws, size_t ws_size,
                              hipStream_t stream)
{
    (void)in_sizes; (void)n_in; (void)out_size;
    const float* node_feats = (const float*)d_in[0];
    const float* edge_feats = (const float*)d_in[1];
    const float* glob_feats = (const float*)d_in[2];
    const int* edge_index   = (const int*)d_in[3];
    const int* batch        = (const int*)d_in[4];
    const float* Wf[9] = {
        (const float*)d_in[5],  (const float*)d_in[6],  (const float*)d_in[7],
        (const float*)d_in[8],  (const float*)d_in[9],  (const float*)d_in[10],
        (const float*)d_in[11], (const float*)d_in[12], (const float*)d_in[13],
    };
    const int Wn[9] = { HID*HID, HID*HID, HID*HID,
                        HID*4*HID, HID*3*HID, HID*3*HID,
                        HID*HID, HID*HID, HID*HID };

    const int* src = edge_index;        // edge_index[0]
    const int* dst = edge_index + NE;   // edge_index[1]

    float* out_n = (float*)d_out;                       // [NN,256] f32
    float* out_e = out_n + (size_t)NN * HID;            // [NE,256] f32
    float* out_g = out_e + (size_t)NE * HID;            // [NG,256] f32

    // ws layout. Zero-init region first -> single memsetAsync (~0.3 MB).
    char* ws = (char*)d_ws;
    size_t off = 0;
    auto alloc = [&](size_t bytes) -> char* {
        char* p = ws + off; off += (bytes + 255) & ~(size_t)255; return p;
    };
    float* e2g_sum = (float*)alloc((size_t)NG * HID * 4);
    int* cnt_dst   = (int*)alloc((size_t)NN * 4);
    int* fill_cnt  = (int*)alloc((size_t)NN * 4);
    int* cnt_eg    = (int*)alloc((size_t)NG * 4);
    int* cnt_ng    = (int*)alloc((size_t)NG * 4);
    size_t zero_bytes = off;
    hipMemsetAsync(d_ws, 0, zero_bytes, stream);

    int* rowstart_dst        = (int*)alloc((size_t)(NN + 1) * 4);
    int* noderow             = (int*)alloc((size_t)(NG + 1) * 4);
    int* eids                = (int*)alloc((size_t)NE * 4);
    int* be                  = (int*)alloc((size_t)NE * 4);
    unsigned short* n1       = (unsigned short*)alloc((size_t)NN * HID * 2);
    unsigned short* g1       = (unsigned short*)alloc((size_t)NG * HID * 2);
    unsigned short* e2n_mean = (unsigned short*)alloc((size_t)NN * HID * 2);
    unsigned short* n_mid    = (unsigned short*)alloc((size_t)NN * HID * 2);
    unsigned short* n2g_mean = (unsigned short*)alloc((size_t)NG * HID * 2);
    unsigned short* e2g_mean = (unsigned short*)alloc((size_t)NG * HID * 2);
    unsigned short* g_mid    = (unsigned short*)alloc((size_t)NG * HID * 2);
    unsigned short* Wb[9];
    for (int i = 0; i < 9; i++) Wb[i] = (unsigned short*)alloc((size_t)Wn[i] * 2);

    // Fast path: bf16 e-stream (e1/e_mid share one 102 MB buffer; edge mega-kernel
    // runs pass1 in place on it and pass2 out of it while L2-hot).
    const size_t ebuf_bytes = (size_t)NE * HID * 2;
    const bool fast = (off + ebuf_bytes) <= ws_size;
    unsigned short* ebuf = fast ? (unsigned short*)alloc(ebuf_bytes) : nullptr;

    // Fallback aliases into d_out:
    float* e1_f32    = out_e;   // stage-1 edge activations, f32, in place
    float* e_mid_f32 = out_e;   // edge-MLP output, f32, in place (identity rows)

    // weights -> bf16 (9 tiny launches, 1M elements total)
    for (int i = 0; i < 9; i++)
        cvt_w_kernel<<<(Wn[i] + 255) / 256, 256, 0, stream>>>(Wf[i], Wb[i], Wn[i]);

    // graph/CSR setup (all tiny)
    be_counts_kernel<<<(NE + 255) / 256, 256, 0, stream>>>(src, dst, batch, be, cnt_dst, cnt_eg);
    node_counts_kernel<<<(NN + 255) / 256, 256, 0, stream>>>(batch, cnt_ng);
    scan_kernel<<<1, 1024, 0, stream>>>(cnt_dst, rowstart_dst, NN);
    scan_kernel<<<1, 1024, 0, stream>>>(cnt_ng, noderow, NG);
    fill_csr_kernel<<<(NE + 255) / 256, 256, 0, stream>>>(dst, rowstart_dst, fill_cnt, eids);

    auto launch_gemm = [&](const ASpec& A, const unsigned short* W,
                           void* o, int of32, const float* resid, int M) {
        gemm_ssp_kernel<<<(M + 127) / 128, 512, 0, stream>>>(A, W, o, of32, resid, M);
    };
    auto launch_fused2 = [&](const ASpec& A, const unsigned short* W1, unsigned short* mid,
                             const unsigned short* W2, const float* resid, float* o2, int M) {
        gemm_ssp_fused2_kernel<<<(M + 127) / 128, 512, 0, stream>>>(A, W1, mid, W2, resid, o2, M);
    };

    // stage 1: lin_*_1 + ssp (f32 inputs -> generic kernel)
    { ASpec a{}; a.base[0] = node_feats; a.f32mask = 1; a.nblocks = 1;
      launch_gemm(a, Wb[0], n1, 0, nullptr, NN); }
    { ASpec a{}; a.base[0] = edge_feats; a.f32mask = 1; a.nblocks = 1;
      if (fast) launch_gemm(a, Wb[1], ebuf, 0, nullptr, NE);      // e1 bf16
      else      launch_gemm(a, Wb[1], e1_f32, 1, nullptr, NE); }  // e1 f32 in d_out
    { ASpec a{}; a.base[0] = glob_feats; a.f32mask = 1; a.nblocks = 1;
      launch_gemm(a, Wb[2], g1, 0, nullptr, NG); }

    // EdgeModel + lin_e_2 fused: pass1 K=1024 -> ebuf bf16 (in place), pass2 -> out_e
    const void* emid_src; int emid_f32;
    if (fast) {
        ASpec a{};
        a.base[0] = n1;   a.idx[0] = src;
        a.base[1] = n1;   a.idx[1] = dst;
        a.base[2] = ebuf; a.idx[2] = nullptr;
        a.base[3] = g1;   a.idx[3] = be;
        a.f32mask = 0; a.nblocks = 4;
        launch_fused2(a, Wb[3], ebuf, Wb[7], edge_feats, out_e, NE);
        emid_src = ebuf; emid_f32 = 0;
    } else {
        ASpec a{};
        a.base[0] = n1;     a.idx[0] = src;
        a.base[1] = n1;     a.idx[1] = dst;
        a.base[2] = e1_f32; a.idx[2] = nullptr;
        a.base[3] = g1;     a.idx[3] = be;
        a.f32mask = 0b0100; a.nblocks = 4;
        launch_gemm(a, Wb[3], e_mid_f32, 1, nullptr, NE);
        emid_src = e_mid_f32; emid_f32 = 1;
    }

    // scatter-means via gather / LDS bins (no bulk global atomics)
    e2n_mean_kernel<<<NN, 256, 0, stream>>>(emid_src, emid_f32, rowstart_dst, eids, e2n_mean);
    e2g_bin_kernel<<<E2G_CHUNKS * 4, 256, 0, stream>>>(emid_src, emid_f32, be, e2g_sum);
    e2g_mean_kernel<<<(NG * HID + 255) / 256, 256, 0, stream>>>(e2g_sum, cnt_eg, e2g_mean);

    // NodeModel + lin_n_2 fused: K=768 -> n_mid bf16, pass2 -> out_n
    { ASpec a{};
      a.base[0] = n1;
      a.base[1] = e2n_mean;
      a.base[2] = g1; a.idx[2] = batch;
      a.f32mask = 0; a.nblocks = 3;
      launch_fused2(a, Wb[4], n_mid, Wb[6], node_feats, out_n, NN); }

    // nodes -> graphs mean (batch sorted -> contiguous segments, no atomics)
    n2g_mean_kernel<<<NG, 256, 0, stream>>>(n_mid, noderow, n2g_mean);

    // GlobalModel + lin_g_2 fused: K=768 -> g_mid bf16, pass2 -> out_g
    { ASpec a{};
      a.base[0] = n2g_mean; a.base[1] = e2g_mean; a.base[2] = g1;
      a.f32mask = 0; a.nblocks = 3;
      launch_fused2(a, Wb[5], g_mid, Wb[8], glob_feats, out_g, NG); }

    // fallback-only: separate final edge GEMM (f32 e_mid in place on out_e)
    if (!fast) {
        ASpec a{}; a.base[0] = e_mid_f32; a.f32mask = 1; a.nblocks = 1;
        launch_gemm(a, Wb[7], out_e, 1, edge_feats, NE);
    }
}